// Round 1
// baseline (13708.624 us; speedup 1.0000x reference)
//
#include <hip/hip_runtime.h>

#define B_ 64
#define S_ 512
#define D_ 256
#define H_ 128
#define M_ 64
#define N_ (B_ * S_)                 // 32768 nodes
#define YSZ ((size_t)N_ * H_)        // 4194304 floats
#define ADJSZ ((size_t)B_ * S_ * S_) // 16777216 floats

__device__ __forceinline__ float fast_tanh(float x) {
  float cx = fminf(fmaxf(x, -10.0f), 10.0f);
  float e = __builtin_amdgcn_exp2f(cx * 2.8853900817779268f); // e^{2x}
  return (e - 1.0f) * __builtin_amdgcn_rcpf(e + 1.0f);
}
__device__ __forceinline__ float fast_sigmoid(float x) {
  float cx = fminf(fmaxf(x, -30.0f), 30.0f);
  float e = __builtin_amdgcn_exp2f(cx * -1.4426950408889634f); // e^{-x}
  return __builtin_amdgcn_rcpf(1.0f + e);
}

// ---------------------------------------------------------------- zero adj
__global__ void kzero(float4* __restrict__ p, int n4) {
  int i = blockIdx.x * blockDim.x + threadIdx.x;
  int stride = gridDim.x * blockDim.x;
  float4 z = {0.f, 0.f, 0.f, 0.f};
  for (; i < n4; i += stride) p[i] = z;
}

// ------------------------------------------- K1: P0 = x @ Wih0^T + (bih0+bhh0)
// C[32768,128] = X[32768,256] * W[128,256]^T ; tile 128x128, K-chunk 32.
__global__ __launch_bounds__(256) void k1_gemm(
    const float* __restrict__ x, const float* __restrict__ W,
    const float* __restrict__ bih, const float* __restrict__ bhh,
    float* __restrict__ P0) {
  __shared__ float Xs[32][132];  // [kk][r]
  __shared__ float Ws[32][132];  // [kk][j]
  const int t = threadIdx.x;
  const int ty = t >> 4, tx = t & 15;
  const int n0 = blockIdx.x * 128;
  float acc[8][8];
#pragma unroll
  for (int i = 0; i < 8; ++i)
#pragma unroll
    for (int j = 0; j < 8; ++j) acc[i][j] = 0.f;

  for (int kc = 0; kc < 256; kc += 32) {
    __syncthreads();
#pragma unroll
    for (int l = 0; l < 4; ++l) {
      int idx = t + l * 256;          // 0..1023
      int r = idx >> 3, f4 = idx & 7; // 128 rows x 8 float4
      float4 v = *(const float4*)&x[(size_t)(n0 + r) * 256 + kc + f4 * 4];
      Xs[f4 * 4 + 0][r] = v.x; Xs[f4 * 4 + 1][r] = v.y;
      Xs[f4 * 4 + 2][r] = v.z; Xs[f4 * 4 + 3][r] = v.w;
      float4 wv = *(const float4*)&W[(size_t)r * 256 + kc + f4 * 4];
      Ws[f4 * 4 + 0][r] = wv.x; Ws[f4 * 4 + 1][r] = wv.y;
      Ws[f4 * 4 + 2][r] = wv.z; Ws[f4 * 4 + 3][r] = wv.w;
    }
    __syncthreads();
#pragma unroll
    for (int kk = 0; kk < 32; ++kk) {
      float4 xa = *(const float4*)&Xs[kk][ty * 8];
      float4 xb = *(const float4*)&Xs[kk][ty * 8 + 4];
      float4 wa = *(const float4*)&Ws[kk][tx * 8];
      float4 wb = *(const float4*)&Ws[kk][tx * 8 + 4];
      float xr[8] = {xa.x, xa.y, xa.z, xa.w, xb.x, xb.y, xb.z, xb.w};
      float wr[8] = {wa.x, wa.y, wa.z, wa.w, wb.x, wb.y, wb.z, wb.w};
#pragma unroll
      for (int i = 0; i < 8; ++i)
#pragma unroll
        for (int j = 0; j < 8; ++j) acc[i][j] += xr[i] * wr[j];
    }
  }
  float bias[8];
#pragma unroll
  for (int j = 0; j < 8; ++j) bias[j] = bih[tx * 8 + j] + bhh[tx * 8 + j];
#pragma unroll
  for (int i = 0; i < 8; ++i) {
    float4 s0 = make_float4(acc[i][0] + bias[0], acc[i][1] + bias[1],
                            acc[i][2] + bias[2], acc[i][3] + bias[3]);
    float4 s1 = make_float4(acc[i][4] + bias[4], acc[i][5] + bias[5],
                            acc[i][6] + bias[6], acc[i][7] + bias[7]);
    size_t base = (size_t)(n0 + ty * 8 + i) * 128 + tx * 8;
    *(float4*)&P0[base] = s0;
    *(float4*)&P0[base + 4] = s1;
  }
}

// ------------------------- K2: sequential 2-layer graph RNN, one block per batch row
// thread: j = tid>>2 (neuron), q = tid&3 (k-quarter). Weights in registers.
__global__ __launch_bounds__(512) void k2_graphrnn(
    const float* __restrict__ P0, const float* __restrict__ Whh0,
    const float* __restrict__ Wih1, const float* __restrict__ Whh1,
    const float* __restrict__ bih1, const float* __restrict__ bhh1,
    const int* __restrict__ mask, float* __restrict__ Y) {
  __shared__ float h0[2][128];
  __shared__ float h1[2][128];
  const int tid = threadIdx.x;
  const int j = tid >> 2, q = tid & 3;
  const int kb = q * 32;
  const int b = blockIdx.x;
  float w0[32], w1[32], w2[32];
#pragma unroll
  for (int k = 0; k < 32; ++k) {
    w0[k] = Whh0[j * 128 + kb + k];
    w1[k] = Wih1[j * 128 + kb + k];
    w2[k] = Whh1[j * 128 + kb + k];
  }
  const float b1c = bih1[j] + bhh1[j];
  if (tid < 128) { h0[0][tid] = 0.f; h1[0][tid] = 0.f; }
  __syncthreads();
  int cur = 0;
  float p0v = P0[(size_t)b * 512 * 128 + j];
  for (int t = 0; t < 512; ++t) {
    int tn = (t + 1 < 512) ? t + 1 : t;
    float p0n = P0[((size_t)b * 512 + tn) * 128 + j];
    float mk = (float)mask[b * 512 + t];
    // layer 0
    float acc = 0.f;
#pragma unroll
    for (int g = 0; g < 8; ++g) {
      float4 xv = *(const float4*)&h0[cur][kb + g * 4];
      acc += w0[g * 4 + 0] * xv.x + w0[g * 4 + 1] * xv.y +
             w0[g * 4 + 2] * xv.z + w0[g * 4 + 3] * xv.w;
    }
    acc += __shfl_xor(acc, 1);
    acc += __shfl_xor(acc, 2);
    float y0 = fast_tanh(acc + p0v);
    if (q == 0) h0[cur ^ 1][j] = y0;
    __syncthreads();
    // layer 1
    float acc2 = 0.f;
#pragma unroll
    for (int g = 0; g < 8; ++g) {
      float4 xv = *(const float4*)&h0[cur ^ 1][kb + g * 4];
      float4 hv = *(const float4*)&h1[cur][kb + g * 4];
      acc2 += w1[g * 4 + 0] * xv.x + w1[g * 4 + 1] * xv.y +
              w1[g * 4 + 2] * xv.z + w1[g * 4 + 3] * xv.w;
      acc2 += w2[g * 4 + 0] * hv.x + w2[g * 4 + 1] * hv.y +
              w2[g * 4 + 2] * hv.z + w2[g * 4 + 3] * hv.w;
    }
    acc2 += __shfl_xor(acc2, 1);
    acc2 += __shfl_xor(acc2, 2);
    float y1 = fast_tanh(acc2 + b1c);
    if (q == 0) h1[cur ^ 1][j] = y1;
    __syncthreads();
    if (tid < 128) Y[((size_t)b * 512 + t) * 128 + tid] = h1[cur ^ 1][tid] * mk;
    cur ^= 1;
    p0v = p0n;
  }
}

// ------------------------- K3: edge autoregressive RNN. 64 nodes/WG, lane=node,
// 8 waves x 16-neuron slices. State in XOR-swizzled LDS; weights via wave-uniform loads.
__global__ __launch_bounds__(512, 2) void k3_edgernn(
    const float* __restrict__ Y, const float* __restrict__ Wih0,
    const float* __restrict__ Whh0, const float* __restrict__ bih0,
    const float* __restrict__ bhh0, const float* __restrict__ Wih1,
    const float* __restrict__ Whh1, const float* __restrict__ bih1,
    const float* __restrict__ bhh1, const float* __restrict__ clsW,
    const float* __restrict__ clsb, float* __restrict__ adj) {
  extern __shared__ float sm[];
  float* Asm = sm;              // 64 nodes x 64 (swizzled granules)  : 4096
  float* Hbuf = sm + 4096;      // 4 x [64 nodes x 128] h0a,h0b,h1a,h1b: 32768
  float* psum = sm + 36864;     // 8 x 64                              : 512
  const int tid = threadIdx.x;
  const int w = tid >> 6, n = tid & 63;
  const int j0 = w * 16;
  const int node0 = blockIdx.x * 64;
  const int i_pos = (node0 + n) & 511;
  const int mval = min(i_pos, 64);

  // init: A=0, h0a = gs (=masked Y), h1a = 0
  for (int idx = tid; idx < 4096; idx += 512) Asm[idx] = 0.f;
  for (int idx = tid; idx < 8192; idx += 512) {
    int nn = idx >> 7, k = idx & 127;
    Hbuf[(nn << 7) + (((k >> 2) ^ (nn & 7)) << 2) + (k & 3)] =
        Y[(size_t)node0 * 128 + idx];
    Hbuf[16384 + idx] = 0.f;
  }
  float b0c[16], b1c[16], cw[16];
#pragma unroll
  for (int jj = 0; jj < 16; ++jj) {
    b0c[jj] = bih0[j0 + jj] + bhh0[j0 + jj];
    b1c[jj] = bih1[j0 + jj] + bhh1[j0 + jj];
    cw[jj] = clsW[j0 + jj];
  }
  const float cb = clsb[0];
  __syncthreads();

  int cur = 0;
  for (int step = 0; step < 64; ++step) {
    float* h0c = Hbuf + cur * 8192;
    float* h0n = Hbuf + (cur ^ 1) * 8192;
    float* h1c = Hbuf + 16384 + cur * 8192;
    float* h1n = Hbuf + 16384 + (cur ^ 1) * 8192;
    // -------- layer 0: n0 = tanh(Wih0@A + Whh0@h0 + b0)
    float acc[16];
#pragma unroll
    for (int jj = 0; jj < 16; ++jj) acc[jj] = b0c[jj];
    {
      const float4* Wp = (const float4*)Wih0;  // row j: 16 float4
      for (int g = 0; g < 16; ++g) {
        float4 xv = *(const float4*)&Asm[(n << 6) + ((g ^ (n & 7)) << 2)];
        float4 wv[16];
#pragma unroll
        for (int jj = 0; jj < 16; ++jj) wv[jj] = Wp[(j0 + jj) * 16 + g];
#pragma unroll
        for (int jj = 0; jj < 16; ++jj)
          acc[jj] += wv[jj].x * xv.x + wv[jj].y * xv.y + wv[jj].z * xv.z +
                     wv[jj].w * xv.w;
      }
    }
    {
      const float4* Wp = (const float4*)Whh0;  // row j: 32 float4
      for (int g = 0; g < 32; ++g) {
        float4 xv = *(const float4*)&h0c[(n << 7) + ((g ^ (n & 7)) << 2)];
        float4 wv[16];
#pragma unroll
        for (int jj = 0; jj < 16; ++jj) wv[jj] = Wp[(j0 + jj) * 32 + g];
#pragma unroll
        for (int jj = 0; jj < 16; ++jj)
          acc[jj] += wv[jj].x * xv.x + wv[jj].y * xv.y + wv[jj].z * xv.z +
                     wv[jj].w * xv.w;
      }
    }
#pragma unroll
    for (int jj = 0; jj < 16; ++jj) acc[jj] = fast_tanh(acc[jj]);
#pragma unroll
    for (int gg = 0; gg < 4; ++gg) {
      float4 v = make_float4(acc[gg * 4], acc[gg * 4 + 1], acc[gg * 4 + 2],
                             acc[gg * 4 + 3]);
      int g = (j0 >> 2) + gg;
      *(float4*)&h0n[(n << 7) + ((g ^ (n & 7)) << 2)] = v;
    }
    __syncthreads();
    // -------- layer 1: n1 = tanh(Wih1@n0 + Whh1@h1 + b1)
    float acc2[16];
#pragma unroll
    for (int jj = 0; jj < 16; ++jj) acc2[jj] = b1c[jj];
    {
      const float4* Wp = (const float4*)Wih1;
      for (int g = 0; g < 32; ++g) {
        float4 xv = *(const float4*)&h0n[(n << 7) + ((g ^ (n & 7)) << 2)];
        float4 wv[16];
#pragma unroll
        for (int jj = 0; jj < 16; ++jj) wv[jj] = Wp[(j0 + jj) * 32 + g];
#pragma unroll
        for (int jj = 0; jj < 16; ++jj)
          acc2[jj] += wv[jj].x * xv.x + wv[jj].y * xv.y + wv[jj].z * xv.z +
                      wv[jj].w * xv.w;
      }
    }
    {
      const float4* Wp = (const float4*)Whh1;
      for (int g = 0; g < 32; ++g) {
        float4 xv = *(const float4*)&h1c[(n << 7) + ((g ^ (n & 7)) << 2)];
        float4 wv[16];
#pragma unroll
        for (int jj = 0; jj < 16; ++jj) wv[jj] = Wp[(j0 + jj) * 32 + g];
#pragma unroll
        for (int jj = 0; jj < 16; ++jj)
          acc2[jj] += wv[jj].x * xv.x + wv[jj].y * xv.y + wv[jj].z * xv.z +
                      wv[jj].w * xv.w;
      }
    }
    float part = 0.f;
#pragma unroll
    for (int jj = 0; jj < 16; ++jj) {
      float v = fast_tanh(acc2[jj]);
      acc2[jj] = v;
      part += cw[jj] * v;
    }
#pragma unroll
    for (int gg = 0; gg < 4; ++gg) {
      float4 v = make_float4(acc2[gg * 4], acc2[gg * 4 + 1], acc2[gg * 4 + 2],
                             acc2[gg * 4 + 3]);
      int g = (j0 >> 2) + gg;
      *(float4*)&h1n[(n << 7) + ((g ^ (n & 7)) << 2)] = v;
    }
    psum[(w << 6) + n] = part;
    __syncthreads();
    if (w == 0) {
      float s = cb;
#pragma unroll
      for (int p = 0; p < 8; ++p) s += psum[(p << 6) + n];
      s = fast_sigmoid(s);
      if (step < mval)
        Asm[(n << 6) + (((step >> 2) ^ (n & 7)) << 2) + (step & 3)] = s;
    }
    __syncthreads();
    cur ^= 1;
  }
  // scatter band into adj: out[b, r, c=i] = A[b, i, k], r = max(0,i-64)+k, k<min(i,64)
  for (int idx = tid; idx < 4096; idx += 512) {
    int nn = idx >> 6, k = idx & 63;
    int nd = node0 + nn;
    int bb = nd >> 9, ii = nd & 511;
    int mm = min(ii, 64);
    if (k < mm) {
      float v = Asm[(nn << 6) + (((k >> 2) ^ (nn & 7)) << 2) + (k & 3)];
      int r = max(0, ii - 64) + k;
      adj[((size_t)bb * 512 + r) * 512 + ii] = v;
    }
  }
}

extern "C" void kernel_launch(void* const* d_in, const int* in_sizes, int n_in,
                              void* d_out, int out_size, void* d_ws,
                              size_t ws_size, hipStream_t stream) {
  const float* x = (const float*)d_in[0];
  const int* mask = (const int*)d_in[1];
  const float* gWih0 = (const float*)d_in[2];
  const float* gWhh0 = (const float*)d_in[3];
  const float* gbih0 = (const float*)d_in[4];
  const float* gbhh0 = (const float*)d_in[5];
  const float* gWih1 = (const float*)d_in[6];
  const float* gWhh1 = (const float*)d_in[7];
  const float* gbih1 = (const float*)d_in[8];
  const float* gbhh1 = (const float*)d_in[9];
  const float* eWih0 = (const float*)d_in[10];
  const float* eWhh0 = (const float*)d_in[11];
  const float* ebih0 = (const float*)d_in[12];
  const float* ebhh0 = (const float*)d_in[13];
  const float* eWih1 = (const float*)d_in[14];
  const float* eWhh1 = (const float*)d_in[15];
  const float* ebih1 = (const float*)d_in[16];
  const float* ebhh1 = (const float*)d_in[17];
  const float* clsW = (const float*)d_in[18];
  const float* clsb = (const float*)d_in[19];
  float* out = (float*)d_out;
  float* Y = out;
  float* adj = out + YSZ;
  float* P0 = adj;  // scratch overlay in adj region; zeroed before K3

  // P0 = x @ Wih0^T + (bih0 + bhh0)
  hipLaunchKernelGGL(k1_gemm, dim3(256), dim3(256), 0, stream, x, gWih0, gbih0,
                     gbhh0, P0);
  // graph RNN (both layers, sequential over S), writes masked Y
  hipLaunchKernelGGL(k2_graphrnn, dim3(64), dim3(512), 0, stream, P0, gWhh0,
                     gWih1, gWhh1, gbih1, gbhh1, mask, Y);
  // zero adj (also wipes P0 scratch)
  hipLaunchKernelGGL(kzero, dim3(2048), dim3(256), 0, stream, (float4*)adj,
                     (int)(ADJSZ / 4));
  // edge RNN + banded scatter
  hipFuncSetAttribute(reinterpret_cast<const void*>(k3_edgernn),
                      hipFuncAttributeMaxDynamicSharedMemorySize, 149504);
  hipLaunchKernelGGL(k3_edgernn, dim3(512), dim3(512), 149504, stream, Y, eWih0,
                     eWhh0, ebih0, ebhh0, eWih1, eWhh1, ebih1, ebhh1, clsW,
                     clsb, adj);
}

// Round 2
// 1746.438 us; speedup vs baseline: 7.8495x; 7.8495x over previous
//
#include <hip/hip_runtime.h>

#define B_ 64
#define S_ 512
#define D_ 256
#define H_ 128
#define M_ 64
#define N_ (B_ * S_)                 // 32768 nodes
#define YSZ ((size_t)N_ * H_)        // 4194304 floats
#define ADJSZ ((size_t)B_ * S_ * S_) // 16777216 floats

typedef __attribute__((ext_vector_type(8))) short bf16x8;
typedef __attribute__((ext_vector_type(4))) float f32x4;

#define MFMA16(a, b, c) __builtin_amdgcn_mfma_f32_16x16x32_bf16(a, b, c, 0, 0, 0)

// weight frag store: 8 n-tiles x 14 k-chunks, 64 lanes x 16B each
#define WFRAGS (8 * 14)
#define WBYTES ((size_t)WFRAGS * 64 * 16)  // 114688 per array (hi, lo)

__device__ __forceinline__ float fast_tanh(float x) {
  float cx = fminf(fmaxf(x, -10.0f), 10.0f);
  float e = __builtin_amdgcn_exp2f(cx * 2.8853900817779268f); // e^{2x}
  return (e - 1.0f) * __builtin_amdgcn_rcpf(e + 1.0f);
}
__device__ __forceinline__ float fast_sigmoid(float x) {
  float cx = fminf(fmaxf(x, -30.0f), 30.0f);
  float e = __builtin_amdgcn_exp2f(cx * -1.4426950408889634f); // e^{-x}
  return __builtin_amdgcn_rcpf(1.0f + e);
}

__device__ __forceinline__ unsigned short f2bf(float x) {
  unsigned u = __float_as_uint(x);
  unsigned r = u + 0x7FFFu + ((u >> 16) & 1u);
  return (unsigned short)(r >> 16);
}
__device__ __forceinline__ float bf2f(unsigned short h) {
  return __uint_as_float(((unsigned)h) << 16);
}

// store value split into hi/lo bf16 arrays at (row,col), Kc cols, XOR-swizzled 16B granules
__device__ __forceinline__ void st_split(char* basehi, char* baselo, int row,
                                         int col, int Kc, float v) {
  unsigned short h = f2bf(v);
  unsigned short lo = f2bf(v - bf2f(h));
  int off = row * Kc * 2 + ((((col >> 3) ^ (row & 7)) << 4) | ((col & 7) << 1));
  *(unsigned short*)(basehi + off) = h;
  *(unsigned short*)(baselo + off) = lo;
}

// ---------------------------------------------------------------- zero adj
__global__ void kzero(float4* __restrict__ p, int n4) {
  int i = blockIdx.x * blockDim.x + threadIdx.x;
  int stride = gridDim.x * blockDim.x;
  float4 z = {0.f, 0.f, 0.f, 0.f};
  for (; i < n4; i += stride) p[i] = z;
}

// ---------------- K0: build pre-swizzled bf16 hi/lo weight fragments in ws
// fid = ntg*14 + kc; kc<6 -> W0cat row j cols kc*32.. ; kc>=6 -> W1cat cols (kc-6)*32..
// lane holds rows j = ntg*16 + (lane&15), k = kbase + (lane>>4)*8 + 0..7 (16B)
__global__ __launch_bounds__(256) void k0_prep(
    const float* __restrict__ eWih0, const float* __restrict__ eWhh0,
    const float* __restrict__ eWih1, const float* __restrict__ eWhh1,
    unsigned short* __restrict__ Wh, unsigned short* __restrict__ Wl) {
  int t = blockIdx.x * 256 + threadIdx.x;
  if (t >= WFRAGS * 64) return;
  int fid = t >> 6, lane = t & 63;
  int ntg = fid / 14, kc = fid % 14;
  int j = ntg * 16 + (lane & 15);
  int kbase = (kc < 6 ? kc : kc - 6) * 32 + (lane >> 4) * 8;
  unsigned hi2[4], lo2[4];
#pragma unroll
  for (int ii = 0; ii < 4; ++ii) {
    unsigned hp = 0, lp = 0;
#pragma unroll
    for (int s = 0; s < 2; ++s) {
      int k = kbase + ii * 2 + s;
      float wv;
      if (kc < 6)
        wv = (k < 64) ? eWih0[j * 64 + k] : eWhh0[j * 128 + (k - 64)];
      else
        wv = (k < 128) ? eWih1[j * 128 + k] : eWhh1[j * 128 + (k - 128)];
      unsigned short h = f2bf(wv);
      unsigned short l = f2bf(wv - bf2f(h));
      hp |= ((unsigned)h) << (16 * s);
      lp |= ((unsigned)l) << (16 * s);
    }
    hi2[ii] = hp;
    lo2[ii] = lp;
  }
  uint4* dh = (uint4*)(Wh) + fid * 64 + lane;
  uint4* dl = (uint4*)(Wl) + fid * 64 + lane;
  *dh = make_uint4(hi2[0], hi2[1], hi2[2], hi2[3]);
  *dl = make_uint4(lo2[0], lo2[1], lo2[2], lo2[3]);
}

// ------------------------------------------- K1: P0 = x @ Wih0^T + (bih0+bhh0)
__global__ __launch_bounds__(256) void k1_gemm(
    const float* __restrict__ x, const float* __restrict__ W,
    const float* __restrict__ bih, const float* __restrict__ bhh,
    float* __restrict__ P0) {
  __shared__ float Xs[32][132];
  __shared__ float Ws[32][132];
  const int t = threadIdx.x;
  const int ty = t >> 4, tx = t & 15;
  const int n0 = blockIdx.x * 128;
  float acc[8][8];
#pragma unroll
  for (int i = 0; i < 8; ++i)
#pragma unroll
    for (int j = 0; j < 8; ++j) acc[i][j] = 0.f;

  for (int kc = 0; kc < 256; kc += 32) {
    __syncthreads();
#pragma unroll
    for (int l = 0; l < 4; ++l) {
      int idx = t + l * 256;
      int r = idx >> 3, f4 = idx & 7;
      float4 v = *(const float4*)&x[(size_t)(n0 + r) * 256 + kc + f4 * 4];
      Xs[f4 * 4 + 0][r] = v.x; Xs[f4 * 4 + 1][r] = v.y;
      Xs[f4 * 4 + 2][r] = v.z; Xs[f4 * 4 + 3][r] = v.w;
      float4 wv = *(const float4*)&W[(size_t)r * 256 + kc + f4 * 4];
      Ws[f4 * 4 + 0][r] = wv.x; Ws[f4 * 4 + 1][r] = wv.y;
      Ws[f4 * 4 + 2][r] = wv.z; Ws[f4 * 4 + 3][r] = wv.w;
    }
    __syncthreads();
#pragma unroll
    for (int kk = 0; kk < 32; ++kk) {
      float4 xa = *(const float4*)&Xs[kk][ty * 8];
      float4 xb = *(const float4*)&Xs[kk][ty * 8 + 4];
      float4 wa = *(const float4*)&Ws[kk][tx * 8];
      float4 wb = *(const float4*)&Ws[kk][tx * 8 + 4];
      float xr[8] = {xa.x, xa.y, xa.z, xa.w, xb.x, xb.y, xb.z, xb.w};
      float wr[8] = {wa.x, wa.y, wa.z, wa.w, wb.x, wb.y, wb.z, wb.w};
#pragma unroll
      for (int i = 0; i < 8; ++i)
#pragma unroll
        for (int j = 0; j < 8; ++j) acc[i][j] += xr[i] * wr[j];
    }
  }
  float bias[8];
#pragma unroll
  for (int j = 0; j < 8; ++j) bias[j] = bih[tx * 8 + j] + bhh[tx * 8 + j];
#pragma unroll
  for (int i = 0; i < 8; ++i) {
    float4 s0 = make_float4(acc[i][0] + bias[0], acc[i][1] + bias[1],
                            acc[i][2] + bias[2], acc[i][3] + bias[3]);
    float4 s1 = make_float4(acc[i][4] + bias[4], acc[i][5] + bias[5],
                            acc[i][6] + bias[6], acc[i][7] + bias[7]);
    size_t base = (size_t)(n0 + ty * 8 + i) * 128 + tx * 8;
    *(float4*)&P0[base] = s0;
    *(float4*)&P0[base + 4] = s1;
  }
}

// ------------------------- K2: sequential 2-layer graph RNN (unchanged, passed)
__global__ __launch_bounds__(512) void k2_graphrnn(
    const float* __restrict__ P0, const float* __restrict__ Whh0,
    const float* __restrict__ Wih1, const float* __restrict__ Whh1,
    const float* __restrict__ bih1, const float* __restrict__ bhh1,
    const int* __restrict__ mask, float* __restrict__ Y) {
  __shared__ float h0[2][128];
  __shared__ float h1[2][128];
  const int tid = threadIdx.x;
  const int j = tid >> 2, q = tid & 3;
  const int kb = q * 32;
  const int b = blockIdx.x;
  float w0[32], w1[32], w2[32];
#pragma unroll
  for (int k = 0; k < 32; ++k) {
    w0[k] = Whh0[j * 128 + kb + k];
    w1[k] = Wih1[j * 128 + kb + k];
    w2[k] = Whh1[j * 128 + kb + k];
  }
  const float b1c = bih1[j] + bhh1[j];
  if (tid < 128) { h0[0][tid] = 0.f; h1[0][tid] = 0.f; }
  __syncthreads();
  int cur = 0;
  float p0v = P0[(size_t)b * 512 * 128 + j];
  for (int t = 0; t < 512; ++t) {
    int tn = (t + 1 < 512) ? t + 1 : t;
    float p0n = P0[((size_t)b * 512 + tn) * 128 + j];
    float mk = (float)mask[b * 512 + t];
    float acc = 0.f;
#pragma unroll
    for (int g = 0; g < 8; ++g) {
      float4 xv = *(const float4*)&h0[cur][kb + g * 4];
      acc += w0[g * 4 + 0] * xv.x + w0[g * 4 + 1] * xv.y +
             w0[g * 4 + 2] * xv.z + w0[g * 4 + 3] * xv.w;
    }
    acc += __shfl_xor(acc, 1);
    acc += __shfl_xor(acc, 2);
    float y0 = fast_tanh(acc + p0v);
    if (q == 0) h0[cur ^ 1][j] = y0;
    __syncthreads();
    float acc2 = 0.f;
#pragma unroll
    for (int g = 0; g < 8; ++g) {
      float4 xv = *(const float4*)&h0[cur ^ 1][kb + g * 4];
      float4 hv = *(const float4*)&h1[cur][kb + g * 4];
      acc2 += w1[g * 4 + 0] * xv.x + w1[g * 4 + 1] * xv.y +
              w1[g * 4 + 2] * xv.z + w1[g * 4 + 3] * xv.w;
      acc2 += w2[g * 4 + 0] * hv.x + w2[g * 4 + 1] * hv.y +
              w2[g * 4 + 2] * hv.z + w2[g * 4 + 3] * hv.w;
    }
    acc2 += __shfl_xor(acc2, 1);
    acc2 += __shfl_xor(acc2, 2);
    float y1 = fast_tanh(acc2 + b1c);
    if (q == 0) h1[cur ^ 1][j] = y1;
    __syncthreads();
    if (tid < 128) Y[((size_t)b * 512 + t) * 128 + tid] = h1[cur ^ 1][tid] * mk;
    cur ^= 1;
    p0v = p0n;
  }
}

// ------------------------- K3 v2: edge RNN via MFMA, 3-term bf16 hi/lo split.
// 64 nodes/block, 8 waves: wave (mg=w&1, ng=w>>1) owns m-tiles {2mg,2mg+1},
// n-tiles {2ng,2ng+1}. hi-weight frags resident in VGPR; lo frags streamed.
// LDS: A(hi/lo) 16K, N0(hi/lo)x2 64K, N1(hi/lo)x2 64K, psum 1K = 148480 B.
#define LDS_A_HI 0
#define LDS_A_LO 8192
#define LDS_N0HI 16384
#define LDS_N0LO 49152
#define LDS_N1HI 81920
#define LDS_N1LO 114688
#define LDS_PSUM 147456
#define LDS_TOTAL 148480

__global__ __launch_bounds__(512, 2) void k3_edge_mfma(
    const float* __restrict__ Y, const unsigned short* __restrict__ Wh,
    const unsigned short* __restrict__ Wl, const float* __restrict__ bih0,
    const float* __restrict__ bhh0, const float* __restrict__ bih1,
    const float* __restrict__ bhh1, const float* __restrict__ clsW,
    const float* __restrict__ clsb, float* __restrict__ adj) {
  extern __shared__ char sm[];
  char* Ahi = sm + LDS_A_HI;
  char* Alo = sm + LDS_A_LO;
  float* psum = (float*)(sm + LDS_PSUM);

  const int tid = threadIdx.x;
  const int w = tid >> 6, l = tid & 63;
  const int mg = w & 1, ng = w >> 1;
  const int colL = l & 15, q = l >> 4;
  const int ghash = colL & 7;
  const int node0 = blockIdx.x * 64;

  // ---- init LDS: A=0, N1[0]=0, N0[0]=split(Y)
  for (int i = tid; i < 4096; i += 512) ((unsigned*)(sm + LDS_A_HI))[i] = 0u;
  for (int i = tid; i < 4096; i += 512) ((unsigned*)(sm + LDS_N1HI))[i] = 0u;
  for (int i = tid; i < 4096; i += 512) ((unsigned*)(sm + LDS_N1LO))[i] = 0u;
  for (int i = tid; i < 8192; i += 512) {
    int nn = i >> 7, k = i & 127;
    float v = Y[(size_t)(node0 + nn) * 128 + k];
    st_split(sm + LDS_N0HI, sm + LDS_N0LO, nn, k, 128, v);
  }

  // ---- resident hi-weight fragments (28 x 16B = 112 VGPR)
  bf16x8 Wr[28];
#pragma unroll
  for (int nt = 0; nt < 2; ++nt)
#pragma unroll
    for (int kc = 0; kc < 14; ++kc)
      Wr[nt * 14 + kc] =
          ((const bf16x8*)Wh)[(size_t)(((ng * 2 + nt) * 14) + kc) * 64 + l];

  // ---- per-lane constants
  float b0v[2], b1v[2], cwv[2];
#pragma unroll
  for (int nt = 0; nt < 2; ++nt) {
    int cg = (2 * ng + nt) * 16 + colL;
    b0v[nt] = bih0[cg] + bhh0[cg];
    b1v[nt] = bih1[cg] + bhh1[cg];
    cwv[nt] = clsW[cg];
  }
  const float cbias = clsb[0];
  const int ipos = (node0 & 511) + l;  // column index i (block never spans b)
  const int mval = min(ipos, 64);
  const int badj = node0 >> 9;

  __syncthreads();

  int p = 0, r1 = 0;
  for (int step = 0; step < 64; ++step) {
    char* n0rd_hi = sm + LDS_N0HI + p * 16384;
    char* n0rd_lo = sm + LDS_N0LO + p * 16384;
    char* n0wr_hi = sm + LDS_N0HI + (p ^ 1) * 16384;
    char* n0wr_lo = sm + LDS_N0LO + (p ^ 1) * 16384;
    char* n1rd_hi = sm + LDS_N1HI + r1 * 16384;
    char* n1rd_lo = sm + LDS_N1LO + r1 * 16384;
    char* n1wr_hi = sm + LDS_N1HI + (r1 ^ 1) * 16384;
    char* n1wr_lo = sm + LDS_N1LO + (r1 ^ 1) * 16384;

    // ================= P0: n0 = tanh([A|h0] @ W0^T + b0)
    f32x4 acc[2][2];
#pragma unroll
    for (int mt = 0; mt < 2; ++mt)
#pragma unroll
      for (int nt = 0; nt < 2; ++nt) {
        float b = b0v[nt];
        acc[mt][nt] = (f32x4){b, b, b, b};
      }
#pragma unroll
    for (int kc = 0; kc < 6; ++kc) {
      const char* bhi = (kc < 2) ? Ahi : n0rd_hi;
      const char* blo = (kc < 2) ? Alo : n0rd_lo;
      const int Kc = (kc < 2) ? 64 : 128;
      const int cb8 = (kc < 2) ? kc * 4 : (kc - 2) * 4;
      bf16x8 ah[2], al[2], bl[2];
#pragma unroll
      for (int mt = 0; mt < 2; ++mt) {
        int row = mg * 32 + mt * 16 + colL;
        int g = (cb8 + q) ^ ghash;
        ah[mt] = *(const bf16x8*)(bhi + row * Kc * 2 + (g << 4));
        al[mt] = *(const bf16x8*)(blo + row * Kc * 2 + (g << 4));
      }
#pragma unroll
      for (int nt = 0; nt < 2; ++nt)
        bl[nt] =
            ((const bf16x8*)Wl)[(size_t)(((ng * 2 + nt) * 14) + kc) * 64 + l];
#pragma unroll
      for (int mt = 0; mt < 2; ++mt)
#pragma unroll
        for (int nt = 0; nt < 2; ++nt) {
          acc[mt][nt] = MFMA16(ah[mt], Wr[nt * 14 + kc], acc[mt][nt]);
          acc[mt][nt] = MFMA16(al[mt], Wr[nt * 14 + kc], acc[mt][nt]);
          acc[mt][nt] = MFMA16(ah[mt], bl[nt], acc[mt][nt]);
        }
    }
#pragma unroll
    for (int mt = 0; mt < 2; ++mt)
#pragma unroll
      for (int nt = 0; nt < 2; ++nt)
#pragma unroll
        for (int rg = 0; rg < 4; ++rg) {
          float v = fast_tanh(acc[mt][nt][rg]);
          int row = mg * 32 + mt * 16 + q * 4 + rg;
          int col = (2 * ng + nt) * 16 + colL;
          st_split(n0wr_hi, n0wr_lo, row, col, 128, v);
        }
    __syncthreads();  // bar A: n0 visible

    // ================= P1: n1 = tanh([n0|h1] @ W1^T + b1)
    f32x4 acc2[2][2];
#pragma unroll
    for (int mt = 0; mt < 2; ++mt)
#pragma unroll
      for (int nt = 0; nt < 2; ++nt) {
        float b = b1v[nt];
        acc2[mt][nt] = (f32x4){b, b, b, b};
      }
#pragma unroll
    for (int kc = 0; kc < 8; ++kc) {
      const char* bhi = (kc < 4) ? n0wr_hi : n1rd_hi;
      const char* blo = (kc < 4) ? n0wr_lo : n1rd_lo;
      const int cb8 = (kc < 4) ? kc * 4 : (kc - 4) * 4;
      bf16x8 ah[2], al[2], bl[2];
#pragma unroll
      for (int mt = 0; mt < 2; ++mt) {
        int row = mg * 32 + mt * 16 + colL;
        int g = (cb8 + q) ^ ghash;
        ah[mt] = *(const bf16x8*)(bhi + row * 256 + (g << 4));
        al[mt] = *(const bf16x8*)(blo + row * 256 + (g << 4));
      }
#pragma unroll
      for (int nt = 0; nt < 2; ++nt)
        bl[nt] = ((const bf16x8*)
                      Wl)[(size_t)(((ng * 2 + nt) * 14) + 6 + kc) * 64 + l];
#pragma unroll
      for (int mt = 0; mt < 2; ++mt)
#pragma unroll
        for (int nt = 0; nt < 2; ++nt) {
          acc2[mt][nt] = MFMA16(ah[mt], Wr[nt * 14 + 6 + kc], acc2[mt][nt]);
          acc2[mt][nt] = MFMA16(al[mt], Wr[nt * 14 + 6 + kc], acc2[mt][nt]);
          acc2[mt][nt] = MFMA16(ah[mt], bl[nt], acc2[mt][nt]);
        }
    }
    float pa[2][4];
#pragma unroll
    for (int mt = 0; mt < 2; ++mt)
#pragma unroll
      for (int rg = 0; rg < 4; ++rg) pa[mt][rg] = 0.f;
#pragma unroll
    for (int mt = 0; mt < 2; ++mt)
#pragma unroll
      for (int nt = 0; nt < 2; ++nt)
#pragma unroll
        for (int rg = 0; rg < 4; ++rg) {
          float v = fast_tanh(acc2[mt][nt][rg]);
          pa[mt][rg] += cwv[nt] * v;
          int row = mg * 32 + mt * 16 + q * 4 + rg;
          int col = (2 * ng + nt) * 16 + colL;
          st_split(n1wr_hi, n1wr_lo, row, col, 128, v);
        }
    // reduce cls partials over the 16 col-lanes
#pragma unroll
    for (int mt = 0; mt < 2; ++mt)
#pragma unroll
      for (int rg = 0; rg < 4; ++rg) {
        float s = pa[mt][rg];
        s += __shfl_xor(s, 1);
        s += __shfl_xor(s, 2);
        s += __shfl_xor(s, 4);
        s += __shfl_xor(s, 8);
        pa[mt][rg] = s;
      }
#pragma unroll
    for (int ii = 0; ii < 8; ++ii)
      if (colL == ii) {
        int mt = ii >> 2, rg = ii & 3;
        int row = mg * 32 + mt * 16 + q * 4 + rg;
        psum[ng * 64 + row] = pa[mt][rg];
      }
    __syncthreads();  // bar B: psum + n1 visible

    if (w == 0) {
      float s = cbias + psum[l] + psum[64 + l] + psum[128 + l] + psum[192 + l];
      float sg = fast_sigmoid(s);
      if (step < mval) {
        st_split(Ahi, Alo, l, step, 64, sg);
        int r = max(0, ipos - 64) + step;
        adj[((size_t)badj * 512 + r) * 512 + ipos] = sg;
      }
    }
    __syncthreads();  // bar C: A visible for next step
    p ^= 1;
    r1 ^= 1;
  }
}

// ------------------------- K3 fallback (f32, round-1 version) if ws too small
__global__ __launch_bounds__(512, 2) void k3_edgernn_f32(
    const float* __restrict__ Y, const float* __restrict__ Wih0,
    const float* __restrict__ Whh0, const float* __restrict__ bih0,
    const float* __restrict__ bhh0, const float* __restrict__ Wih1,
    const float* __restrict__ Whh1, const float* __restrict__ bih1,
    const float* __restrict__ bhh1, const float* __restrict__ clsW,
    const float* __restrict__ clsb, float* __restrict__ adj) {
  extern __shared__ float smf[];
  float* Asm = smf;
  float* Hbuf = smf + 4096;
  float* psum = smf + 36864;
  const int tid = threadIdx.x;
  const int w = tid >> 6, n = tid & 63;
  const int j0 = w * 16;
  const int node0 = blockIdx.x * 64;
  const int i_pos = (node0 + n) & 511;
  const int mval = min(i_pos, 64);
  for (int idx = tid; idx < 4096; idx += 512) Asm[idx] = 0.f;
  for (int idx = tid; idx < 8192; idx += 512) {
    int nn = idx >> 7, k = idx & 127;
    Hbuf[(nn << 7) + (((k >> 2) ^ (nn & 7)) << 2) + (k & 3)] =
        Y[(size_t)node0 * 128 + idx];
    Hbuf[16384 + idx] = 0.f;
  }
  float b0c[16], b1c[16], cw[16];
#pragma unroll
  for (int jj = 0; jj < 16; ++jj) {
    b0c[jj] = bih0[j0 + jj] + bhh0[j0 + jj];
    b1c[jj] = bih1[j0 + jj] + bhh1[j0 + jj];
    cw[jj] = clsW[j0 + jj];
  }
  const float cb = clsb[0];
  __syncthreads();
  int cur = 0;
  for (int step = 0; step < 64; ++step) {
    float* h0c = Hbuf + cur * 8192;
    float* h0n = Hbuf + (cur ^ 1) * 8192;
    float* h1c = Hbuf + 16384 + cur * 8192;
    float* h1n = Hbuf + 16384 + (cur ^ 1) * 8192;
    float acc[16];
#pragma unroll
    for (int jj = 0; jj < 16; ++jj) acc[jj] = b0c[jj];
    {
      const float4* Wp = (const float4*)Wih0;
      for (int g = 0; g < 16; ++g) {
        float4 xv = *(const float4*)&Asm[(n << 6) + ((g ^ (n & 7)) << 2)];
        float4 wv[16];
#pragma unroll
        for (int jj = 0; jj < 16; ++jj) wv[jj] = Wp[(j0 + jj) * 16 + g];
#pragma unroll
        for (int jj = 0; jj < 16; ++jj)
          acc[jj] += wv[jj].x * xv.x + wv[jj].y * xv.y + wv[jj].z * xv.z +
                     wv[jj].w * xv.w;
      }
    }
    {
      const float4* Wp = (const float4*)Whh0;
      for (int g = 0; g < 32; ++g) {
        float4 xv = *(const float4*)&h0c[(n << 7) + ((g ^ (n & 7)) << 2)];
        float4 wv[16];
#pragma unroll
        for (int jj = 0; jj < 16; ++jj) wv[jj] = Wp[(j0 + jj) * 32 + g];
#pragma unroll
        for (int jj = 0; jj < 16; ++jj)
          acc[jj] += wv[jj].x * xv.x + wv[jj].y * xv.y + wv[jj].z * xv.z +
                     wv[jj].w * xv.w;
      }
    }
#pragma unroll
    for (int jj = 0; jj < 16; ++jj) acc[jj] = fast_tanh(acc[jj]);
#pragma unroll
    for (int gg = 0; gg < 4; ++gg) {
      float4 v = make_float4(acc[gg * 4], acc[gg * 4 + 1], acc[gg * 4 + 2],
                             acc[gg * 4 + 3]);
      int g = (j0 >> 2) + gg;
      *(float4*)&h0n[(n << 7) + ((g ^ (n & 7)) << 2)] = v;
    }
    __syncthreads();
    float acc2[16];
#pragma unroll
    for (int jj = 0; jj < 16; ++jj) acc2[jj] = b1c[jj];
    {
      const float4* Wp = (const float4*)Wih1;
      for (int g = 0; g < 32; ++g) {
        float4 xv = *(const float4*)&h0n[(n << 7) + ((g ^ (n & 7)) << 2)];
        float4 wv[16];
#pragma unroll
        for (int jj = 0; jj < 16; ++jj) wv[jj] = Wp[(j0 + jj) * 32 + g];
#pragma unroll
        for (int jj = 0; jj < 16; ++jj)
          acc2[jj] += wv[jj].x * xv.x + wv[jj].y * xv.y + wv[jj].z * xv.z +
                      wv[jj].w * xv.w;
      }
    }
    {
      const float4* Wp = (const float4*)Whh1;
      for (int g = 0; g < 32; ++g) {
        float4 xv = *(const float4*)&h1c[(n << 7) + ((g ^ (n & 7)) << 2)];
        float4 wv[16];
#pragma unroll
        for (int jj = 0; jj < 16; ++jj) wv[jj] = Wp[(j0 + jj) * 32 + g];
#pragma unroll
        for (int jj = 0; jj < 16; ++jj)
          acc2[jj] += wv[jj].x * xv.x + wv[jj].y * xv.y + wv[jj].z * xv.z +
                      wv[jj].w * xv.w;
      }
    }
    float part = 0.f;
#pragma unroll
    for (int jj = 0; jj < 16; ++jj) {
      float v = fast_tanh(acc2[jj]);
      acc2[jj] = v;
      part += cw[jj] * v;
    }
#pragma unroll
    for (int gg = 0; gg < 4; ++gg) {
      float4 v = make_float4(acc2[gg * 4], acc2[gg * 4 + 1], acc2[gg * 4 + 2],
                             acc2[gg * 4 + 3]);
      int g = (j0 >> 2) + gg;
      *(float4*)&h1n[(n << 7) + ((g ^ (n & 7)) << 2)] = v;
    }
    psum[(w << 6) + n] = part;
    __syncthreads();
    if (w == 0) {
      float s = cb;
#pragma unroll
      for (int pp = 0; pp < 8; ++pp) s += psum[(pp << 6) + n];
      s = fast_sigmoid(s);
      if (step < mval)
        Asm[(n << 6) + (((step >> 2) ^ (n & 7)) << 2) + (step & 3)] = s;
    }
    __syncthreads();
    cur ^= 1;
  }
  for (int idx = tid; idx < 4096; idx += 512) {
    int nn = idx >> 6, k = idx & 63;
    int nd = node0 + nn;
    int bb = nd >> 9, ii = nd & 511;
    int mm = min(ii, 64);
    if (k < mm) {
      float v = Asm[(nn << 6) + (((k >> 2) ^ (nn & 7)) << 2) + (k & 3)];
      int r = max(0, ii - 64) + k;
      adj[((size_t)bb * 512 + r) * 512 + ii] = v;
    }
  }
}

extern "C" void kernel_launch(void* const* d_in, const int* in_sizes, int n_in,
                              void* d_out, int out_size, void* d_ws,
                              size_t ws_size, hipStream_t stream) {
  const float* x = (const float*)d_in[0];
  const int* mask = (const int*)d_in[1];
  const float* gWih0 = (const float*)d_in[2];
  const float* gWhh0 = (const float*)d_in[3];
  const float* gbih0 = (const float*)d_in[4];
  const float* gbhh0 = (const float*)d_in[5];
  const float* gWih1 = (const float*)d_in[6];
  const float* gWhh1 = (const float*)d_in[7];
  const float* gbih1 = (const float*)d_in[8];
  const float* gbhh1 = (const float*)d_in[9];
  const float* eWih0 = (const float*)d_in[10];
  const float* eWhh0 = (const float*)d_in[11];
  const float* ebih0 = (const float*)d_in[12];
  const float* ebhh0 = (const float*)d_in[13];
  const float* eWih1 = (const float*)d_in[14];
  const float* eWhh1 = (const float*)d_in[15];
  const float* ebih1 = (const float*)d_in[16];
  const float* ebhh1 = (const float*)d_in[17];
  const float* clsW = (const float*)d_in[18];
  const float* clsb = (const float*)d_in[19];
  float* out = (float*)d_out;
  float* Y = out;
  float* adj = out + YSZ;
  float* P0 = adj;  // scratch overlay in adj region; wiped by kzero before k3

  const bool use_mfma = (ws_size >= 2 * WBYTES);

  if (use_mfma) {
    unsigned short* Wh = (unsigned short*)d_ws;
    unsigned short* Wl = (unsigned short*)((char*)d_ws + WBYTES);
    hipLaunchKernelGGL(k0_prep, dim3(28), dim3(256), 0, stream, eWih0, eWhh0,
                       eWih1, eWhh1, Wh, Wl);
    hipLaunchKernelGGL(k1_gemm, dim3(256), dim3(256), 0, stream, x, gWih0,
                       gbih0, gbhh0, P0);
    hipLaunchKernelGGL(k2_graphrnn, dim3(64), dim3(512), 0, stream, P0, gWhh0,
                       gWih1, gWhh1, gbih1, gbhh1, mask, Y);
    hipLaunchKernelGGL(kzero, dim3(2048), dim3(256), 0, stream, (float4*)adj,
                       (int)(ADJSZ / 4));
    hipFuncSetAttribute(reinterpret_cast<const void*>(k3_edge_mfma),
                        hipFuncAttributeMaxDynamicSharedMemorySize, LDS_TOTAL);
    hipLaunchKernelGGL(k3_edge_mfma, dim3(512), dim3(512), LDS_TOTAL, stream,
                       Y, Wh, Wl, ebih0, ebhh0, ebih1, ebhh1, clsW, clsb, adj);
  } else {
    hipLaunchKernelGGL(k1_gemm, dim3(256), dim3(256), 0, stream, x, gWih0,
                       gbih0, gbhh0, P0);
    hipLaunchKernelGGL(k2_graphrnn, dim3(64), dim3(512), 0, stream, P0, gWhh0,
                       gWih1, gWhh1, gbih1, gbhh1, mask, Y);
    hipLaunchKernelGGL(kzero, dim3(2048), dim3(256), 0, stream, (float4*)adj,
                       (int)(ADJSZ / 4));
    hipFuncSetAttribute(reinterpret_cast<const void*>(k3_edgernn_f32),
                        hipFuncAttributeMaxDynamicSharedMemorySize, 149504);
    hipLaunchKernelGGL(k3_edgernn_f32, dim3(512), dim3(512), 149504, stream, Y,
                       eWih0, eWhh0, ebih0, ebhh0, eWih1, eWhh1, ebih1, ebhh1,
                       clsW, clsb, adj);
  }
}

// Round 3
// 1177.433 us; speedup vs baseline: 11.6428x; 1.4833x over previous
//
#include <hip/hip_runtime.h>

#define B_ 64
#define S_ 512
#define D_ 256
#define H_ 128
#define M_ 64
#define N_ (B_ * S_)                 // 32768 nodes
#define YSZ ((size_t)N_ * H_)        // 4194304 floats
#define ADJSZ ((size_t)B_ * S_ * S_) // 16777216 floats

typedef __attribute__((ext_vector_type(8))) _Float16 f16x8;
typedef __attribute__((ext_vector_type(4))) float f32x4;

#define MFMAH(a, b, c) __builtin_amdgcn_mfma_f32_16x16x32_f16(a, b, c, 0, 0, 0)

// weight frag store: 8 n-tiles x 14 k-chunks, 64 lanes x 16B each (f16)
#define WFRAGS (8 * 14)
#define WBYTES ((size_t)WFRAGS * 64 * 16)  // 114688

__device__ __forceinline__ float fast_tanh(float x) {
  float cx = fminf(fmaxf(x, -10.0f), 10.0f);
  float e = __builtin_amdgcn_exp2f(cx * 2.8853900817779268f); // e^{2x}
  return (e - 1.0f) * __builtin_amdgcn_rcpf(e + 1.0f);
}
__device__ __forceinline__ float fast_sigmoid(float x) {
  float cx = fminf(fmaxf(x, -30.0f), 30.0f);
  float e = __builtin_amdgcn_exp2f(cx * -1.4426950408889634f); // e^{-x}
  return __builtin_amdgcn_rcpf(1.0f + e);
}

// element index in a [rows][Kc] f16 array, XOR-swizzled 16B (8-elem) granules
__device__ __forceinline__ int sw(int row, int col, int Kc) {
  return row * Kc + ((((col >> 3) ^ (row & 7)) << 3) | (col & 7));
}

// ---------------------------------------------------------------- zero adj
__global__ void kzero(float4* __restrict__ p, int n4) {
  int i = blockIdx.x * blockDim.x + threadIdx.x;
  int stride = gridDim.x * blockDim.x;
  float4 z = {0.f, 0.f, 0.f, 0.f};
  for (; i < n4; i += stride) p[i] = z;
}

// ---------------- K0: pack f16 weight fragments (native MFMA B-frag order)
// fid = ntg*14 + kc; kc<6 -> W0cat=[Wih0|Whh0] cols kc*32.. ; kc>=6 -> W1cat
// lane: row j = ntg*16 + (lane&15), k = kbase + (lane>>4)*8 + {0..7}
__global__ __launch_bounds__(256) void k0_prep(
    const float* __restrict__ eWih0, const float* __restrict__ eWhh0,
    const float* __restrict__ eWih1, const float* __restrict__ eWhh1,
    unsigned short* __restrict__ Wf) {
  int t = blockIdx.x * 256 + threadIdx.x;
  if (t >= WFRAGS * 64) return;
  int fid = t >> 6, lane = t & 63;
  int ntg = fid / 14, kc = fid % 14;
  int j = ntg * 16 + (lane & 15);
  int kbase = (kc < 6 ? kc : kc - 6) * 32 + (lane >> 4) * 8;
  unsigned pk[4];
#pragma unroll
  for (int ii = 0; ii < 4; ++ii) {
    unsigned p2 = 0;
#pragma unroll
    for (int s = 0; s < 2; ++s) {
      int k = kbase + ii * 2 + s;
      float wv;
      if (kc < 6)
        wv = (k < 64) ? eWih0[j * 64 + k] : eWhh0[j * 128 + (k - 64)];
      else
        wv = (k < 128) ? eWih1[j * 128 + k] : eWhh1[j * 128 + (k - 128)];
      _Float16 h = (_Float16)wv;
      unsigned short us = *(unsigned short*)&h;
      p2 |= ((unsigned)us) << (16 * s);
    }
    pk[ii] = p2;
  }
  ((uint4*)Wf)[fid * 64 + lane] = make_uint4(pk[0], pk[1], pk[2], pk[3]);
}

// ------------------------------------------- K1: P0 = x @ Wih0^T + (bih0+bhh0)
__global__ __launch_bounds__(256) void k1_gemm(
    const float* __restrict__ x, const float* __restrict__ W,
    const float* __restrict__ bih, const float* __restrict__ bhh,
    float* __restrict__ P0) {
  __shared__ float Xs[32][132];
  __shared__ float Ws[32][132];
  const int t = threadIdx.x;
  const int ty = t >> 4, tx = t & 15;
  const int n0 = blockIdx.x * 128;
  float acc[8][8];
#pragma unroll
  for (int i = 0; i < 8; ++i)
#pragma unroll
    for (int j = 0; j < 8; ++j) acc[i][j] = 0.f;

  for (int kc = 0; kc < 256; kc += 32) {
    __syncthreads();
#pragma unroll
    for (int l = 0; l < 4; ++l) {
      int idx = t + l * 256;
      int r = idx >> 3, f4 = idx & 7;
      float4 v = *(const float4*)&x[(size_t)(n0 + r) * 256 + kc + f4 * 4];
      Xs[f4 * 4 + 0][r] = v.x; Xs[f4 * 4 + 1][r] = v.y;
      Xs[f4 * 4 + 2][r] = v.z; Xs[f4 * 4 + 3][r] = v.w;
      float4 wv = *(const float4*)&W[(size_t)r * 256 + kc + f4 * 4];
      Ws[f4 * 4 + 0][r] = wv.x; Ws[f4 * 4 + 1][r] = wv.y;
      Ws[f4 * 4 + 2][r] = wv.z; Ws[f4 * 4 + 3][r] = wv.w;
    }
    __syncthreads();
#pragma unroll
    for (int kk = 0; kk < 32; ++kk) {
      float4 xa = *(const float4*)&Xs[kk][ty * 8];
      float4 xb = *(const float4*)&Xs[kk][ty * 8 + 4];
      float4 wa = *(const float4*)&Ws[kk][tx * 8];
      float4 wb = *(const float4*)&Ws[kk][tx * 8 + 4];
      float xr[8] = {xa.x, xa.y, xa.z, xa.w, xb.x, xb.y, xb.z, xb.w};
      float wr[8] = {wa.x, wa.y, wa.z, wa.w, wb.x, wb.y, wb.z, wb.w};
#pragma unroll
      for (int i = 0; i < 8; ++i)
#pragma unroll
        for (int j = 0; j < 8; ++j) acc[i][j] += xr[i] * wr[j];
    }
  }
  float bias[8];
#pragma unroll
  for (int j = 0; j < 8; ++j) bias[j] = bih[tx * 8 + j] + bhh[tx * 8 + j];
#pragma unroll
  for (int i = 0; i < 8; ++i) {
    float4 s0 = make_float4(acc[i][0] + bias[0], acc[i][1] + bias[1],
                            acc[i][2] + bias[2], acc[i][3] + bias[3]);
    float4 s1 = make_float4(acc[i][4] + bias[4], acc[i][5] + bias[5],
                            acc[i][6] + bias[6], acc[i][7] + bias[7]);
    size_t base = (size_t)(n0 + ty * 8 + i) * 128 + tx * 8;
    *(float4*)&P0[base] = s0;
    *(float4*)&P0[base + 4] = s1;
  }
}

// ------------------------- K2: sequential 2-layer graph RNN (unchanged, passing)
__global__ __launch_bounds__(512) void k2_graphrnn(
    const float* __restrict__ P0, const float* __restrict__ Whh0,
    const float* __restrict__ Wih1, const float* __restrict__ Whh1,
    const float* __restrict__ bih1, const float* __restrict__ bhh1,
    const int* __restrict__ mask, float* __restrict__ Y) {
  __shared__ float h0[2][128];
  __shared__ float h1[2][128];
  const int tid = threadIdx.x;
  const int j = tid >> 2, q = tid & 3;
  const int kb = q * 32;
  const int b = blockIdx.x;
  float w0[32], w1[32], w2[32];
#pragma unroll
  for (int k = 0; k < 32; ++k) {
    w0[k] = Whh0[j * 128 + kb + k];
    w1[k] = Wih1[j * 128 + kb + k];
    w2[k] = Whh1[j * 128 + kb + k];
  }
  const float b1c = bih1[j] + bhh1[j];
  if (tid < 128) { h0[0][tid] = 0.f; h1[0][tid] = 0.f; }
  __syncthreads();
  int cur = 0;
  float p0v = P0[(size_t)b * 512 * 128 + j];
  for (int t = 0; t < 512; ++t) {
    int tn = (t + 1 < 512) ? t + 1 : t;
    float p0n = P0[((size_t)b * 512 + tn) * 128 + j];
    float mk = (float)mask[b * 512 + t];
    float acc = 0.f;
#pragma unroll
    for (int g = 0; g < 8; ++g) {
      float4 xv = *(const float4*)&h0[cur][kb + g * 4];
      acc += w0[g * 4 + 0] * xv.x + w0[g * 4 + 1] * xv.y +
             w0[g * 4 + 2] * xv.z + w0[g * 4 + 3] * xv.w;
    }
    acc += __shfl_xor(acc, 1);
    acc += __shfl_xor(acc, 2);
    float y0 = fast_tanh(acc + p0v);
    if (q == 0) h0[cur ^ 1][j] = y0;
    __syncthreads();
    float acc2 = 0.f;
#pragma unroll
    for (int g = 0; g < 8; ++g) {
      float4 xv = *(const float4*)&h0[cur ^ 1][kb + g * 4];
      float4 hv = *(const float4*)&h1[cur][kb + g * 4];
      acc2 += w1[g * 4 + 0] * xv.x + w1[g * 4 + 1] * xv.y +
              w1[g * 4 + 2] * xv.z + w1[g * 4 + 3] * xv.w;
      acc2 += w2[g * 4 + 0] * hv.x + w2[g * 4 + 1] * hv.y +
              w2[g * 4 + 2] * hv.z + w2[g * 4 + 3] * hv.w;
    }
    acc2 += __shfl_xor(acc2, 1);
    acc2 += __shfl_xor(acc2, 2);
    float y1 = fast_tanh(acc2 + b1c);
    if (q == 0) h1[cur ^ 1][j] = y1;
    __syncthreads();
    if (tid < 128) Y[((size_t)b * 512 + t) * 128 + tid] = h1[cur ^ 1][tid] * mk;
    cur ^= 1;
    p0v = p0n;
  }
}

// ------------------------- K3 v3: edge RNN, single-term f16 MFMA.
// 64 nodes/block, 16 waves (1024 thr): wave w -> ng = w&7 (one 16-feature
// n-tile), mg = w>>3 (32-node half, 2 m-tiles). Weights VGPR-resident
// (14 frags = 56 VGPR). State f16 in XOR-swizzled LDS, double-buffered.
// No in-loop global stores; adj band scattered from LDS at the end.
#define LDSA 0       // A      [64][64]  f16        :  8192 B
#define LDSN0 8192   // n0     2 x [64][128] f16    : 32768 B
#define LDSN1 40960  // n1     2 x [64][128] f16    : 32768 B
#define LDSPS 73728  // psum   [64][8] f32          :  2048 B
#define LDSTOT 75776

__global__ __launch_bounds__(1024, 4) void k3_edge_f16(
    const float* __restrict__ Y, const unsigned short* __restrict__ Wf,
    const float* __restrict__ bih0, const float* __restrict__ bhh0,
    const float* __restrict__ bih1, const float* __restrict__ bhh1,
    const float* __restrict__ clsW, const float* __restrict__ clsb,
    float* __restrict__ adj) {
  extern __shared__ char sm[];
  _Float16* Aq = (_Float16*)(sm + LDSA);
  _Float16* N0 = (_Float16*)(sm + LDSN0);
  _Float16* N1 = (_Float16*)(sm + LDSN1);
  float* psum = (float*)(sm + LDSPS);

  const int tid = threadIdx.x;
  const int w = tid >> 6, l = tid & 63;
  const int ng = w & 7, mg = w >> 3;
  const int colL = l & 15, q = l >> 4;
  const int node0 = blockIdx.x * 64;

  // ---- init: A = 0, N1 (both buffers) = 0, N0 buf0 = f16(Y) swizzled
  for (int i = tid; i < 2048; i += 1024) ((unsigned*)(sm + LDSA))[i] = 0u;
  for (int i = tid; i < 8192; i += 1024) ((unsigned*)(sm + LDSN1))[i] = 0u;
  for (int i = tid; i < 8192; i += 1024) {
    int nn = i >> 7, k = i & 127;
    float v = Y[(size_t)(node0 + nn) * 128 + k];
    N0[sw(nn, k, 128)] = (_Float16)v;
  }

  // ---- resident weight fragments: 14 x 16B = 56 VGPR
  f16x8 Wr[14];
#pragma unroll
  for (int kc = 0; kc < 14; ++kc)
    Wr[kc] = ((const f16x8*)Wf)[(size_t)(ng * 14 + kc) * 64 + l];

  // ---- per-lane constants
  const int cg = ng * 16 + colL;  // output-feature column of this lane
  const float b0v = bih0[cg] + bhh0[cg];
  const float b1v = bih1[cg] + bhh1[cg];
  const float cwv = clsW[cg];
  const float cbias = clsb[0];
  const int ipos = (node0 & 511) + l;  // position within sequence (lane=node)
  const int mval = min(ipos, 64);
  const int badj = node0 >> 9;

  __syncthreads();

  int p = 0;
  for (int step = 0; step < 64; ++step) {
    _Float16* n0rd = N0 + p * 8192;
    _Float16* n0wr = N0 + (p ^ 1) * 8192;
    _Float16* n1rd = N1 + p * 8192;
    _Float16* n1wr = N1 + (p ^ 1) * 8192;

    // ===== P0: n0 = tanh([A | h0] @ W0^T + b0)   (K = 64 + 128)
    f32x4 acc[2];
    acc[0] = (f32x4){b0v, b0v, b0v, b0v};
    acc[1] = acc[0];
#pragma unroll
    for (int kc = 0; kc < 6; ++kc) {
      f16x8 ah[2];
#pragma unroll
      for (int mt = 0; mt < 2; ++mt) {
        int row = mg * 32 + mt * 16 + colL;
        if (kc < 2) {
          int gk = kc * 4 + q;
          ah[mt] = *(const f16x8*)&Aq[row * 64 + ((gk ^ (row & 7)) << 3)];
        } else {
          int gk = (kc - 2) * 4 + q;
          ah[mt] = *(const f16x8*)&n0rd[row * 128 + ((gk ^ (row & 7)) << 3)];
        }
      }
#pragma unroll
      for (int mt = 0; mt < 2; ++mt) acc[mt] = MFMAH(ah[mt], Wr[kc], acc[mt]);
    }
#pragma unroll
    for (int mt = 0; mt < 2; ++mt)
#pragma unroll
      for (int rg = 0; rg < 4; ++rg) {
        float v = fast_tanh(acc[mt][rg]);
        int row = mg * 32 + mt * 16 + q * 4 + rg;
        n0wr[sw(row, cg, 128)] = (_Float16)v;
      }
    __syncthreads();  // bar A: n0 complete

    // ===== P1: n1 = tanh([n0 | h1] @ W1^T + b1)   (K = 128 + 128)
    f32x4 acc2[2];
    acc2[0] = (f32x4){b1v, b1v, b1v, b1v};
    acc2[1] = acc2[0];
#pragma unroll
    for (int kc = 0; kc < 8; ++kc) {
      const _Float16* src = (kc < 4) ? n0wr : n1rd;
      int gk = (kc & 3) * 4 + q;
      f16x8 ah[2];
#pragma unroll
      for (int mt = 0; mt < 2; ++mt) {
        int row = mg * 32 + mt * 16 + colL;
        ah[mt] = *(const f16x8*)&src[row * 128 + ((gk ^ (row & 7)) << 3)];
      }
#pragma unroll
      for (int mt = 0; mt < 2; ++mt)
        acc2[mt] = MFMAH(ah[mt], Wr[6 + kc], acc2[mt]);
    }
    float pa[2][4];
#pragma unroll
    for (int mt = 0; mt < 2; ++mt)
#pragma unroll
      for (int rg = 0; rg < 4; ++rg) {
        float v = fast_tanh(acc2[mt][rg]);
        pa[mt][rg] = cwv * v;
        int row = mg * 32 + mt * 16 + q * 4 + rg;
        n1wr[sw(row, cg, 128)] = (_Float16)v;
      }
    // reduce cls partials across the 16 feature-columns (lane low-4 bits)
#pragma unroll
    for (int mt = 0; mt < 2; ++mt)
#pragma unroll
      for (int rg = 0; rg < 4; ++rg) {
        float s = pa[mt][rg];
        s += __shfl_xor(s, 1);
        s += __shfl_xor(s, 2);
        s += __shfl_xor(s, 4);
        s += __shfl_xor(s, 8);
        pa[mt][rg] = s;
      }
#pragma unroll
    for (int ii = 0; ii < 8; ++ii)
      if (colL == ii) {
        int row = mg * 32 + (ii >> 2) * 16 + q * 4 + (ii & 3);
        psum[row * 8 + ng] = pa[ii >> 2][ii & 3];
      }
    __syncthreads();  // bar B: psum + n1 complete

    // ===== cls: sigmoid + write-back into A (LDS only)
    if (w == 0) {
      float4 s1 = *(const float4*)&psum[l * 8];
      float4 s2 = *(const float4*)&psum[l * 8 + 4];
      float s = cbias + s1.x + s1.y + s1.z + s1.w + s2.x + s2.y + s2.z + s2.w;
      float sg = fast_sigmoid(s);
      if (step < mval)
        Aq[l * 64 + ((((step >> 3) ^ (l & 7)) << 3) | (step & 7))] =
            (_Float16)sg;
    }
    __syncthreads();  // bar C: A visible for next step
    p ^= 1;
  }

  // ---- scatter band into adj from A (f16 -> f32)
  for (int idx = tid; idx < 4096; idx += 1024) {
    int nn = idx >> 6, k = idx & 63;
    int nd = node0 + nn;
    int bb = nd >> 9, ii = nd & 511;
    int mm = min(ii, 64);
    if (k < mm) {
      float v = (float)Aq[sw(nn, k, 64)];
      int r = max(0, ii - 64) + k;
      adj[((size_t)bb * 512 + r) * 512 + ii] = v;
    }
  }
}

// ------------------------- K3 fallback (f32) if ws too small for weight frags
__global__ __launch_bounds__(512, 2) void k3_edgernn_f32(
    const float* __restrict__ Y, const float* __restrict__ Wih0,
    const float* __restrict__ Whh0, const float* __restrict__ bih0,
    const float* __restrict__ bhh0, const float* __restrict__ Wih1,
    const float* __restrict__ Whh1, const float* __restrict__ bih1,
    const float* __restrict__ bhh1, const float* __restrict__ clsW,
    const float* __restrict__ clsb, float* __restrict__ adj) {
  extern __shared__ float smf[];
  float* Asm = smf;
  float* Hbuf = smf + 4096;
  float* psum = smf + 36864;
  const int tid = threadIdx.x;
  const int w = tid >> 6, n = tid & 63;
  const int j0 = w * 16;
  const int node0 = blockIdx.x * 64;
  const int i_pos = (node0 + n) & 511;
  const int mval = min(i_pos, 64);
  for (int idx = tid; idx < 4096; idx += 512) Asm[idx] = 0.f;
  for (int idx = tid; idx < 8192; idx += 512) {
    int nn = idx >> 7, k = idx & 127;
    Hbuf[(nn << 7) + (((k >> 2) ^ (nn & 7)) << 2) + (k & 3)] =
        Y[(size_t)node0 * 128 + idx];
    Hbuf[16384 + idx] = 0.f;
  }
  float b0c[16], b1c[16], cw[16];
#pragma unroll
  for (int jj = 0; jj < 16; ++jj) {
    b0c[jj] = bih0[j0 + jj] + bhh0[j0 + jj];
    b1c[jj] = bih1[j0 + jj] + bhh1[j0 + jj];
    cw[jj] = clsW[j0 + jj];
  }
  const float cb = clsb[0];
  __syncthreads();
  int cur = 0;
  for (int step = 0; step < 64; ++step) {
    float* h0c = Hbuf + cur * 8192;
    float* h0n = Hbuf + (cur ^ 1) * 8192;
    float* h1c = Hbuf + 16384 + cur * 8192;
    float* h1n = Hbuf + 16384 + (cur ^ 1) * 8192;
    float acc[16];
#pragma unroll
    for (int jj = 0; jj < 16; ++jj) acc[jj] = b0c[jj];
    {
      const float4* Wp = (const float4*)Wih0;
      for (int g = 0; g < 16; ++g) {
        float4 xv = *(const float4*)&Asm[(n << 6) + ((g ^ (n & 7)) << 2)];
        float4 wv[16];
#pragma unroll
        for (int jj = 0; jj < 16; ++jj) wv[jj] = Wp[(j0 + jj) * 16 + g];
#pragma unroll
        for (int jj = 0; jj < 16; ++jj)
          acc[jj] += wv[jj].x * xv.x + wv[jj].y * xv.y + wv[jj].z * xv.z +
                     wv[jj].w * xv.w;
      }
    }
    {
      const float4* Wp = (const float4*)Whh0;
      for (int g = 0; g < 32; ++g) {
        float4 xv = *(const float4*)&h0c[(n << 7) + ((g ^ (n & 7)) << 2)];
        float4 wv[16];
#pragma unroll
        for (int jj = 0; jj < 16; ++jj) wv[jj] = Wp[(j0 + jj) * 32 + g];
#pragma unroll
        for (int jj = 0; jj < 16; ++jj)
          acc[jj] += wv[jj].x * xv.x + wv[jj].y * xv.y + wv[jj].z * xv.z +
                     wv[jj].w * xv.w;
      }
    }
#pragma unroll
    for (int jj = 0; jj < 16; ++jj) acc[jj] = fast_tanh(acc[jj]);
#pragma unroll
    for (int gg = 0; gg < 4; ++gg) {
      float4 v = make_float4(acc[gg * 4], acc[gg * 4 + 1], acc[gg * 4 + 2],
                             acc[gg * 4 + 3]);
      int g = (j0 >> 2) + gg;
      *(float4*)&h0n[(n << 7) + ((g ^ (n & 7)) << 2)] = v;
    }
    __syncthreads();
    float acc2[16];
#pragma unroll
    for (int jj = 0; jj < 16; ++jj) acc2[jj] = b1c[jj];
    {
      const float4* Wp = (const float4*)Wih1;
      for (int g = 0; g < 32; ++g) {
        float4 xv = *(const float4*)&h0n[(n << 7) + ((g ^ (n & 7)) << 2)];
        float4 wv[16];
#pragma unroll
        for (int jj = 0; jj < 16; ++jj) wv[jj] = Wp[(j0 + jj) * 32 + g];
#pragma unroll
        for (int jj = 0; jj < 16; ++jj)
          acc2[jj] += wv[jj].x * xv.x + wv[jj].y * xv.y + wv[jj].z * xv.z +
                      wv[jj].w * xv.w;
      }
    }
    {
      const float4* Wp = (const float4*)Whh1;
      for (int g = 0; g < 32; ++g) {
        float4 xv = *(const float4*)&h1c[(n << 7) + ((g ^ (n & 7)) << 2)];
        float4 wv[16];
#pragma unroll
        for (int jj = 0; jj < 16; ++jj) wv[jj] = Wp[(j0 + jj) * 32 + g];
#pragma unroll
        for (int jj = 0; jj < 16; ++jj)
          acc2[jj] += wv[jj].x * xv.x + wv[jj].y * xv.y + wv[jj].z * xv.z +
                      wv[jj].w * xv.w;
      }
    }
    float part = 0.f;
#pragma unroll
    for (int jj = 0; jj < 16; ++jj) {
      float v = fast_tanh(acc2[jj]);
      acc2[jj] = v;
      part += cw[jj] * v;
    }
#pragma unroll
    for (int gg = 0; gg < 4; ++gg) {
      float4 v = make_float4(acc2[gg * 4], acc2[gg * 4 + 1], acc2[gg * 4 + 2],
                             acc2[gg * 4 + 3]);
      int g = (j0 >> 2) + gg;
      *(float4*)&h1n[(n << 7) + ((g ^ (n & 7)) << 2)] = v;
    }
    psum[(w << 6) + n] = part;
    __syncthreads();
    if (w == 0) {
      float s = cb;
#pragma unroll
      for (int pp = 0; pp < 8; ++pp) s += psum[(pp << 6) + n];
      s = fast_sigmoid(s);
      if (step < mval)
        Asm[(n << 6) + (((step >> 2) ^ (n & 7)) << 2) + (step & 3)] = s;
    }
    __syncthreads();
    cur ^= 1;
  }
  for (int idx = tid; idx < 4096; idx += 512) {
    int nn = idx >> 6, k = idx & 63;
    int nd = node0 + nn;
    int bb = nd >> 9, ii = nd & 511;
    int mm = min(ii, 64);
    if (k < mm) {
      float v = Asm[(nn << 6) + (((k >> 2) ^ (nn & 7)) << 2) + (k & 3)];
      int r = max(0, ii - 64) + k;
      adj[((size_t)bb * 512 + r) * 512 + ii] = v;
    }
  }
}

extern "C" void kernel_launch(void* const* d_in, const int* in_sizes, int n_in,
                              void* d_out, int out_size, void* d_ws,
                              size_t ws_size, hipStream_t stream) {
  const float* x = (const float*)d_in[0];
  const int* mask = (const int*)d_in[1];
  const float* gWih0 = (const float*)d_in[2];
  const float* gWhh0 = (const float*)d_in[3];
  const float* gbih0 = (const float*)d_in[4];
  const float* gbhh0 = (const float*)d_in[5];
  const float* gWih1 = (const float*)d_in[6];
  const float* gWhh1 = (const float*)d_in[7];
  const float* gbih1 = (const float*)d_in[8];
  const float* gbhh1 = (const float*)d_in[9];
  const float* eWih0 = (const float*)d_in[10];
  const float* eWhh0 = (const float*)d_in[11];
  const float* ebih0 = (const float*)d_in[12];
  const float* ebhh0 = (const float*)d_in[13];
  const float* eWih1 = (const float*)d_in[14];
  const float* eWhh1 = (const float*)d_in[15];
  const float* ebih1 = (const float*)d_in[16];
  const float* ebhh1 = (const float*)d_in[17];
  const float* clsW = (const float*)d_in[18];
  const float* clsb = (const float*)d_in[19];
  float* out = (float*)d_out;
  float* Y = out;
  float* adj = out + YSZ;
  float* P0 = adj;  // scratch overlay in adj region; wiped by kzero before k3

  const bool use_mfma = (ws_size >= WBYTES);

  if (use_mfma) {
    unsigned short* Wf = (unsigned short*)d_ws;
    hipLaunchKernelGGL(k0_prep, dim3(28), dim3(256), 0, stream, eWih0, eWhh0,
                       eWih1, eWhh1, Wf);
    hipLaunchKernelGGL(k1_gemm, dim3(256), dim3(256), 0, stream, x, gWih0,
                       gbih0, gbhh0, P0);
    hipLaunchKernelGGL(k2_graphrnn, dim3(64), dim3(512), 0, stream, P0, gWhh0,
                       gWih1, gWhh1, gbih1, gbhh1, mask, Y);
    hipLaunchKernelGGL(kzero, dim3(2048), dim3(256), 0, stream, (float4*)adj,
                       (int)(ADJSZ / 4));
    hipFuncSetAttribute(reinterpret_cast<const void*>(k3_edge_f16),
                        hipFuncAttributeMaxDynamicSharedMemorySize, LDSTOT);
    hipLaunchKernelGGL(k3_edge_f16, dim3(512), dim3(1024), LDSTOT, stream, Y,
                       Wf, ebih0, ebhh0, ebih1, ebhh1, clsW, clsb, adj);
  } else {
    hipLaunchKernelGGL(k1_gemm, dim3(256), dim3(256), 0, stream, x, gWih0,
                       gbih0, gbhh0, P0);
    hipLaunchKernelGGL(k2_graphrnn, dim3(64), dim3(512), 0, stream, P0, gWhh0,
                       gWih1, gWhh1, gbih1, gbhh1, mask, Y);
    hipLaunchKernelGGL(kzero, dim3(2048), dim3(256), 0, stream, (float4*)adj,
                       (int)(ADJSZ / 4));
    hipFuncSetAttribute(reinterpret_cast<const void*>(k3_edgernn_f32),
                        hipFuncAttributeMaxDynamicSharedMemorySize, 149504);
    hipLaunchKernelGGL(k3_edgernn_f32, dim3(512), dim3(512), 149504, stream, Y,
                       eWih0, eWhh0, ebih0, ebhh0, eWih1, eWhh1, ebih1, ebhh1,
                       clsW, clsb, adj);
  }
}

// Round 4
// 1166.378 us; speedup vs baseline: 11.7532x; 1.0095x over previous
//
#include <hip/hip_runtime.h>

#define B_ 64
#define S_ 512
#define D_ 256
#define H_ 128
#define M_ 64
#define N_ (B_ * S_)                 // 32768 nodes
#define YSZ ((size_t)N_ * H_)        // 4194304 floats
#define ADJSZ ((size_t)B_ * S_ * S_) // 16777216 floats

typedef __attribute__((ext_vector_type(8))) _Float16 f16x8;
typedef __attribute__((ext_vector_type(2))) _Float16 h2;
typedef __attribute__((ext_vector_type(4))) float f32x4;

#define MFMAH(a, b, c) __builtin_amdgcn_mfma_f32_16x16x32_f16(a, b, c, 0, 0, 0)

// weight frag store: 8 n-tiles x 14 k-chunks, 64 lanes x 16B each (f16)
#define WFRAGS (8 * 14)
#define WBYTES ((size_t)WFRAGS * 64 * 16)  // 114688

__device__ __forceinline__ float fast_tanh(float x) {
  float cx = fminf(fmaxf(x, -10.0f), 10.0f);
  float e = __builtin_amdgcn_exp2f(cx * 2.8853900817779268f); // e^{2x}
  return (e - 1.0f) * __builtin_amdgcn_rcpf(e + 1.0f);
}
__device__ __forceinline__ float fast_sigmoid(float x) {
  float cx = fminf(fmaxf(x, -30.0f), 30.0f);
  float e = __builtin_amdgcn_exp2f(cx * -1.4426950408889634f); // e^{-x}
  return __builtin_amdgcn_rcpf(1.0f + e);
}

// element index in a [rows][Kc] f16 array, XOR-swizzled 16B (8-elem) granules
__device__ __forceinline__ int sw(int row, int col, int Kc) {
  return row * Kc + ((((col >> 3) ^ (row & 7)) << 3) | (col & 7));
}

// ---------------------------------------------------------------- zero adj
__global__ void kzero(float4* __restrict__ p, int n4) {
  int i = blockIdx.x * blockDim.x + threadIdx.x;
  int stride = gridDim.x * blockDim.x;
  float4 z = {0.f, 0.f, 0.f, 0.f};
  for (; i < n4; i += stride) p[i] = z;
}

// ---------------- K0: pack f16 weight fragments (native MFMA B-frag order)
__global__ __launch_bounds__(256) void k0_prep(
    const float* __restrict__ eWih0, const float* __restrict__ eWhh0,
    const float* __restrict__ eWih1, const float* __restrict__ eWhh1,
    unsigned short* __restrict__ Wf) {
  int t = blockIdx.x * 256 + threadIdx.x;
  if (t >= WFRAGS * 64) return;
  int fid = t >> 6, lane = t & 63;
  int ntg = fid / 14, kc = fid % 14;
  int j = ntg * 16 + (lane & 15);
  int kbase = (kc < 6 ? kc : kc - 6) * 32 + (lane >> 4) * 8;
  unsigned pk[4];
#pragma unroll
  for (int ii = 0; ii < 4; ++ii) {
    unsigned p2 = 0;
#pragma unroll
    for (int s = 0; s < 2; ++s) {
      int k = kbase + ii * 2 + s;
      float wv;
      if (kc < 6)
        wv = (k < 64) ? eWih0[j * 64 + k] : eWhh0[j * 128 + (k - 64)];
      else
        wv = (k < 128) ? eWih1[j * 128 + k] : eWhh1[j * 128 + (k - 128)];
      _Float16 h = (_Float16)wv;
      unsigned short us = *(unsigned short*)&h;
      p2 |= ((unsigned)us) << (16 * s);
    }
    pk[ii] = p2;
  }
  ((uint4*)Wf)[fid * 64 + lane] = make_uint4(pk[0], pk[1], pk[2], pk[3]);
}

// ------------------------------------------- K1: P0 = x @ Wih0^T + (bih0+bhh0)
__global__ __launch_bounds__(256) void k1_gemm(
    const float* __restrict__ x, const float* __restrict__ W,
    const float* __restrict__ bih, const float* __restrict__ bhh,
    float* __restrict__ P0) {
  __shared__ float Xs[32][132];
  __shared__ float Ws[32][132];
  const int t = threadIdx.x;
  const int ty = t >> 4, tx = t & 15;
  const int n0 = blockIdx.x * 128;
  float acc[8][8];
#pragma unroll
  for (int i = 0; i < 8; ++i)
#pragma unroll
    for (int j = 0; j < 8; ++j) acc[i][j] = 0.f;

  for (int kc = 0; kc < 256; kc += 32) {
    __syncthreads();
#pragma unroll
    for (int l = 0; l < 4; ++l) {
      int idx = t + l * 256;
      int r = idx >> 3, f4 = idx & 7;
      float4 v = *(const float4*)&x[(size_t)(n0 + r) * 256 + kc + f4 * 4];
      Xs[f4 * 4 + 0][r] = v.x; Xs[f4 * 4 + 1][r] = v.y;
      Xs[f4 * 4 + 2][r] = v.z; Xs[f4 * 4 + 3][r] = v.w;
      float4 wv = *(const float4*)&W[(size_t)r * 256 + kc + f4 * 4];
      Ws[f4 * 4 + 0][r] = wv.x; Ws[f4 * 4 + 1][r] = wv.y;
      Ws[f4 * 4 + 2][r] = wv.z; Ws[f4 * 4 + 3][r] = wv.w;
    }
    __syncthreads();
#pragma unroll
    for (int kk = 0; kk < 32; ++kk) {
      float4 xa = *(const float4*)&Xs[kk][ty * 8];
      float4 xb = *(const float4*)&Xs[kk][ty * 8 + 4];
      float4 wa = *(const float4*)&Ws[kk][tx * 8];
      float4 wb = *(const float4*)&Ws[kk][tx * 8 + 4];
      float xr[8] = {xa.x, xa.y, xa.z, xa.w, xb.x, xb.y, xb.z, xb.w};
      float wr[8] = {wa.x, wa.y, wa.z, wa.w, wb.x, wb.y, wb.z, wb.w};
#pragma unroll
      for (int i = 0; i < 8; ++i)
#pragma unroll
        for (int j = 0; j < 8; ++j) acc[i][j] += xr[i] * wr[j];
    }
  }
  float bias[8];
#pragma unroll
  for (int j = 0; j < 8; ++j) bias[j] = bih[tx * 8 + j] + bhh[tx * 8 + j];
#pragma unroll
  for (int i = 0; i < 8; ++i) {
    float4 s0 = make_float4(acc[i][0] + bias[0], acc[i][1] + bias[1],
                            acc[i][2] + bias[2], acc[i][3] + bias[3]);
    float4 s1 = make_float4(acc[i][4] + bias[4], acc[i][5] + bias[5],
                            acc[i][6] + bias[6], acc[i][7] + bias[7]);
    size_t base = (size_t)(n0 + ty * 8 + i) * 128 + tx * 8;
    *(float4*)&P0[base] = s0;
    *(float4*)&P0[base + 4] = s1;
  }
}

// ------------------------- K2 v2: graph RNN, 4 waves/block, register-resident
// weights, software-pipelined layers (L1 lags L0 by 1 step), 1 barrier/step.
// w0/w1: layer0 rows 0-63/64-127 (Whh0 row f32-resident; bias folded in P0).
// w2/w3: layer1 rows (Wih1 row f16-resident via fdot2; Whh1 row f32-resident).
// State rings in LDS: h0 f32 (recurrent) + h0 f16 (L1 input) + h1 f32.
__global__ __launch_bounds__(256, 1) void k2_v2(
    const float* __restrict__ P0, const float* __restrict__ Whh0,
    const float* __restrict__ Wih1, const float* __restrict__ Whh1,
    const float* __restrict__ bih1, const float* __restrict__ bhh1,
    const int* __restrict__ mask, float* __restrict__ Y) {
  __shared__ __align__(16) float r0f[2][128];
  __shared__ __align__(16) float r1f[2][128];
  __shared__ __align__(16) _Float16 r0h[2][128];
  const int tid = threadIdx.x;
  const int w = tid >> 6, l = tid & 63;
  const int row = (w & 1) * 64 + l;
  const int b = blockIdx.x;
  const bool isL0 = (w < 2);

  // resident weights
  float Wa[128];  // Whh0 row (L0) or Whh1 row (L1)
  h2 Wb[64];      // Wih1 row packed (L1 only)
  {
    const float* src = isL0 ? (Whh0 + row * 128) : (Whh1 + row * 128);
#pragma unroll
    for (int i = 0; i < 32; ++i) {
      float4 v = *(const float4*)&src[i * 4];
      Wa[i * 4 + 0] = v.x; Wa[i * 4 + 1] = v.y;
      Wa[i * 4 + 2] = v.z; Wa[i * 4 + 3] = v.w;
    }
    if (!isL0) {
      const float* s2 = Wih1 + row * 128;
#pragma unroll
      for (int i = 0; i < 64; ++i) {
        h2 t;
        t.x = (_Float16)s2[i * 2];
        t.y = (_Float16)s2[i * 2 + 1];
        Wb[i] = t;
      }
    }
  }
  const float b1c = bih1[row] + bhh1[row];
  if (tid < 128) { r0f[1][tid] = 0.f; r1f[0][tid] = 0.f; }
  __syncthreads();

  float p0v = isL0 ? P0[((size_t)b * 512 + 0) * 128 + row] : 0.f;

  for (int s = 0; s <= 512; ++s) {
    const int cs = s & 1, ps = cs ^ 1;
    if (isL0) {
      if (s < 512) {
        float p0n = (s + 1 < 512)
                        ? P0[((size_t)b * 512 + (s + 1)) * 128 + row]
                        : 0.f;
        float acc = p0v;
        const float4* hp = (const float4*)&r0f[ps][0];
#pragma unroll
        for (int c = 0; c < 32; ++c) {
          float4 hv = hp[c];
          acc += Wa[c * 4 + 0] * hv.x + Wa[c * 4 + 1] * hv.y +
                 Wa[c * 4 + 2] * hv.z + Wa[c * 4 + 3] * hv.w;
        }
        float y = fast_tanh(acc);  // layer-0 bias already folded into P0
        r0f[cs][row] = y;
        r0h[cs][row] = (_Float16)y;
        p0v = p0n;
      }
    } else {
      if (s >= 1) {
        const int t = s - 1;
        float acc = b1c;
        const uint4* yp4 = (const uint4*)&r0h[ps][0];
#pragma unroll
        for (int c8 = 0; c8 < 16; ++c8) {
          uint4 u = yp4[c8];
          h2 a0 = __builtin_bit_cast(h2, u.x);
          h2 a1 = __builtin_bit_cast(h2, u.y);
          h2 a2 = __builtin_bit_cast(h2, u.z);
          h2 a3 = __builtin_bit_cast(h2, u.w);
#if __has_builtin(__builtin_amdgcn_fdot2)
          acc = __builtin_amdgcn_fdot2(Wb[c8 * 4 + 0], a0, acc, false);
          acc = __builtin_amdgcn_fdot2(Wb[c8 * 4 + 1], a1, acc, false);
          acc = __builtin_amdgcn_fdot2(Wb[c8 * 4 + 2], a2, acc, false);
          acc = __builtin_amdgcn_fdot2(Wb[c8 * 4 + 3], a3, acc, false);
#else
          acc += (float)Wb[c8 * 4 + 0].x * (float)a0.x +
                 (float)Wb[c8 * 4 + 0].y * (float)a0.y;
          acc += (float)Wb[c8 * 4 + 1].x * (float)a1.x +
                 (float)Wb[c8 * 4 + 1].y * (float)a1.y;
          acc += (float)Wb[c8 * 4 + 2].x * (float)a2.x +
                 (float)Wb[c8 * 4 + 2].y * (float)a2.y;
          acc += (float)Wb[c8 * 4 + 3].x * (float)a3.x +
                 (float)Wb[c8 * 4 + 3].y * (float)a3.y;
#endif
        }
        const float4* hp = (const float4*)&r1f[ps][0];
#pragma unroll
        for (int c = 0; c < 32; ++c) {
          float4 hv = hp[c];
          acc += Wa[c * 4 + 0] * hv.x + Wa[c * 4 + 1] * hv.y +
                 Wa[c * 4 + 2] * hv.z + Wa[c * 4 + 3] * hv.w;
        }
        float y = fast_tanh(acc);
        r1f[cs][row] = y;
        float mk = (float)mask[b * 512 + t];
        Y[((size_t)b * 512 + t) * 128 + row] = y * mk;
      }
    }
    __syncthreads();
  }
}

// ------------------------- K3 v4: edge RNN, single-term f16 MFMA.
// Changes vs v3: 2 barriers/step (bar C removed via all-wave redundant cls —
// every wave computes sigmoid and writes identical A values, then reads its
// OWN writes, lgkm-ordered); psum layout [8][64] for conflict-free cls reads.
#define LDSA 0       // A      [64][64]  f16        :  8192 B
#define LDSN0 8192   // n0     2 x [64][128] f16    : 32768 B
#define LDSN1 40960  // n1     2 x [64][128] f16    : 32768 B
#define LDSPS 73728  // psum   [8][64] f32          :  2048 B
#define LDSTOT 75776

__global__ __launch_bounds__(1024, 4) void k3_edge_f16(
    const float* __restrict__ Y, const unsigned short* __restrict__ Wf,
    const float* __restrict__ bih0, const float* __restrict__ bhh0,
    const float* __restrict__ bih1, const float* __restrict__ bhh1,
    const float* __restrict__ clsW, const float* __restrict__ clsb,
    float* __restrict__ adj) {
  extern __shared__ char sm[];
  _Float16* Aq = (_Float16*)(sm + LDSA);
  _Float16* N0 = (_Float16*)(sm + LDSN0);
  _Float16* N1 = (_Float16*)(sm + LDSN1);
  float* psum = (float*)(sm + LDSPS);

  const int tid = threadIdx.x;
  const int w = tid >> 6, l = tid & 63;
  const int ng = w & 7, mg = w >> 3;
  const int colL = l & 15, q = l >> 4;
  const int node0 = blockIdx.x * 64;

  // ---- init: A = 0, N1 (both buffers) = 0, N0 buf0 = f16(Y) swizzled
  for (int i = tid; i < 2048; i += 1024) ((unsigned*)(sm + LDSA))[i] = 0u;
  for (int i = tid; i < 8192; i += 1024) ((unsigned*)(sm + LDSN1))[i] = 0u;
  for (int i = tid; i < 8192; i += 1024) {
    int nn = i >> 7, k = i & 127;
    float v = Y[(size_t)(node0 + nn) * 128 + k];
    N0[sw(nn, k, 128)] = (_Float16)v;
  }

  // ---- resident weight fragments: 14 x 16B = 56 VGPR
  f16x8 Wr[14];
#pragma unroll
  for (int kc = 0; kc < 14; ++kc)
    Wr[kc] = ((const f16x8*)Wf)[(size_t)(ng * 14 + kc) * 64 + l];

  // ---- per-lane constants
  const int cg = ng * 16 + colL;
  const float b0v = bih0[cg] + bhh0[cg];
  const float b1v = bih1[cg] + bhh1[cg];
  const float cwv = clsW[cg];
  const float cbias = clsb[0];
  const int ipos = (node0 & 511) + l;
  const int mval = min(ipos, 64);
  const int badj = node0 >> 9;

  __syncthreads();

  int p = 0;
  for (int step = 0; step < 64; ++step) {
    _Float16* n0rd = N0 + p * 8192;
    _Float16* n0wr = N0 + (p ^ 1) * 8192;
    _Float16* n1rd = N1 + p * 8192;
    _Float16* n1wr = N1 + (p ^ 1) * 8192;

    // ===== P0: n0 = tanh([A | h0] @ W0^T + b0)   (K = 64 + 128)
    f32x4 acc[2];
    acc[0] = (f32x4){b0v, b0v, b0v, b0v};
    acc[1] = acc[0];
#pragma unroll
    for (int kc = 0; kc < 6; ++kc) {
      f16x8 ah[2];
#pragma unroll
      for (int mt = 0; mt < 2; ++mt) {
        int row = mg * 32 + mt * 16 + colL;
        if (kc < 2) {
          int gk = kc * 4 + q;
          ah[mt] = *(const f16x8*)&Aq[row * 64 + ((gk ^ (row & 7)) << 3)];
        } else {
          int gk = (kc - 2) * 4 + q;
          ah[mt] = *(const f16x8*)&n0rd[row * 128 + ((gk ^ (row & 7)) << 3)];
        }
      }
#pragma unroll
      for (int mt = 0; mt < 2; ++mt) acc[mt] = MFMAH(ah[mt], Wr[kc], acc[mt]);
    }
#pragma unroll
    for (int mt = 0; mt < 2; ++mt)
#pragma unroll
      for (int rg = 0; rg < 4; ++rg) {
        float v = fast_tanh(acc[mt][rg]);
        int row = mg * 32 + mt * 16 + q * 4 + rg;
        n0wr[sw(row, cg, 128)] = (_Float16)v;
      }
    __syncthreads();  // bar A: n0 complete

    // ===== P1: n1 = tanh([n0 | h1] @ W1^T + b1)   (K = 128 + 128)
    f32x4 acc2[2];
    acc2[0] = (f32x4){b1v, b1v, b1v, b1v};
    acc2[1] = acc2[0];
#pragma unroll
    for (int kc = 0; kc < 8; ++kc) {
      const _Float16* src = (kc < 4) ? n0wr : n1rd;
      int gk = (kc & 3) * 4 + q;
      f16x8 ah[2];
#pragma unroll
      for (int mt = 0; mt < 2; ++mt) {
        int row = mg * 32 + mt * 16 + colL;
        ah[mt] = *(const f16x8*)&src[row * 128 + ((gk ^ (row & 7)) << 3)];
      }
#pragma unroll
      for (int mt = 0; mt < 2; ++mt)
        acc2[mt] = MFMAH(ah[mt], Wr[6 + kc], acc2[mt]);
    }
    float pa[2][4];
#pragma unroll
    for (int mt = 0; mt < 2; ++mt)
#pragma unroll
      for (int rg = 0; rg < 4; ++rg) {
        float v = fast_tanh(acc2[mt][rg]);
        pa[mt][rg] = cwv * v;
        int row = mg * 32 + mt * 16 + q * 4 + rg;
        n1wr[sw(row, cg, 128)] = (_Float16)v;
      }
#pragma unroll
    for (int mt = 0; mt < 2; ++mt)
#pragma unroll
      for (int rg = 0; rg < 4; ++rg) {
        float s = pa[mt][rg];
        s += __shfl_xor(s, 1);
        s += __shfl_xor(s, 2);
        s += __shfl_xor(s, 4);
        s += __shfl_xor(s, 8);
        pa[mt][rg] = s;
      }
#pragma unroll
    for (int ii = 0; ii < 8; ++ii)
      if (colL == ii) {
        int row = mg * 32 + (ii >> 2) * 16 + q * 4 + (ii & 3);
        psum[ng * 64 + row] = pa[ii >> 2][ii & 3];
      }
    __syncthreads();  // bar B: psum + n1 complete

    // ===== cls: ALL waves redundantly compute sigmoid; each wave writes the
    // identical A value for node l, then reads its own writes next step
    // (in-wave lgkm ordering) — no third barrier needed.
    {
      float s = cbias;
#pragma unroll
      for (int pp = 0; pp < 8; ++pp) s += psum[pp * 64 + l];
      float sg = fast_sigmoid(s);
      if (step < mval)
        Aq[l * 64 + ((((step >> 3) ^ (l & 7)) << 3) | (step & 7))] =
            (_Float16)sg;
    }
    p ^= 1;
  }
  __syncthreads();  // make final A + n1 visible for the scatter

  // ---- scatter band into adj from A (f16 -> f32)
  for (int idx = tid; idx < 4096; idx += 1024) {
    int nn = idx >> 6, k = idx & 63;
    int nd = node0 + nn;
    int bb = nd >> 9, ii = nd & 511;
    int mm = min(ii, 64);
    if (k < mm) {
      float v = (float)Aq[sw(nn, k, 64)];
      int r = max(0, ii - 64) + k;
      adj[((size_t)bb * 512 + r) * 512 + ii] = v;
    }
  }
}

extern "C" void kernel_launch(void* const* d_in, const int* in_sizes, int n_in,
                              void* d_out, int out_size, void* d_ws,
                              size_t ws_size, hipStream_t stream) {
  const float* x = (const float*)d_in[0];
  const int* mask = (const int*)d_in[1];
  const float* gWih0 = (const float*)d_in[2];
  const float* gWhh0 = (const float*)d_in[3];
  const float* gbih0 = (const float*)d_in[4];
  const float* gbhh0 = (const float*)d_in[5];
  const float* gWih1 = (const float*)d_in[6];
  const float* gWhh1 = (const float*)d_in[7];
  const float* gbih1 = (const float*)d_in[8];
  const float* gbhh1 = (const float*)d_in[9];
  const float* eWih0 = (const float*)d_in[10];
  const float* eWhh0 = (const float*)d_in[11];
  const float* ebih0 = (const float*)d_in[12];
  const float* ebhh0 = (const float*)d_in[13];
  const float* eWih1 = (const float*)d_in[14];
  const float* eWhh1 = (const float*)d_in[15];
  const float* ebih1 = (const float*)d_in[16];
  const float* ebhh1 = (const float*)d_in[17];
  const float* clsW = (const float*)d_in[18];
  const float* clsb = (const float*)d_in[19];
  float* out = (float*)d_out;
  float* Y = out;
  float* adj = out + YSZ;
  float* P0 = adj;  // scratch overlay in adj region; wiped by kzero before k3

  unsigned short* Wf = (unsigned short*)d_ws;
  hipLaunchKernelGGL(k0_prep, dim3(28), dim3(256), 0, stream, eWih0, eWhh0,
                     eWih1, eWhh1, Wf);
  hipLaunchKernelGGL(k1_gemm, dim3(256), dim3(256), 0, stream, x, gWih0,
                     gbih0, gbhh0, P0);
  hipLaunchKernelGGL(k2_v2, dim3(64), dim3(256), 0, stream, P0, gWhh0, gWih1,
                     gWhh1, gbih1, gbhh1, mask, Y);
  hipLaunchKernelGGL(kzero, dim3(2048), dim3(256), 0, stream, (float4*)adj,
                     (int)(ADJSZ / 4));
  hipFuncSetAttribute(reinterpret_cast<const void*>(k3_edge_f16),
                      hipFuncAttributeMaxDynamicSharedMemorySize, LDSTOT);
  hipLaunchKernelGGL(k3_edge_f16, dim3(512), dim3(1024), LDSTOT, stream, Y,
                     Wf, ebih0, ebhh0, ebih1, ebhh1, clsW, clsb, adj);
}

// Round 5
// 1042.984 us; speedup vs baseline: 13.1437x; 1.1183x over previous
//
#include <hip/hip_runtime.h>

#define B_ 64
#define S_ 512
#define D_ 256
#define H_ 128
#define M_ 64
#define N_ (B_ * S_)                 // 32768 nodes
#define YSZ ((size_t)N_ * H_)        // 4194304 floats
#define ADJSZ ((size_t)B_ * S_ * S_) // 16777216 floats

typedef __attribute__((ext_vector_type(8))) _Float16 f16x8;
typedef __attribute__((ext_vector_type(2))) _Float16 h2;
typedef __attribute__((ext_vector_type(4))) float f32x4;

#define MFMAH(a, b, c) __builtin_amdgcn_mfma_f32_16x16x32_f16(a, b, c, 0, 0, 0)

// weight frag store: 8 n-tiles x 14 k-chunks, 64 lanes x 16B each (f16)
#define WFRAGS (8 * 14)
#define WBYTES ((size_t)WFRAGS * 64 * 16)  // 114688

__device__ __forceinline__ float fast_tanh(float x) {
  // tanh(x) = 1 - 2/(e^{2x}+1), 6 instrs: med3, mul, exp2, add, rcp, fma
  float cx = __builtin_amdgcn_fmed3f(x, -10.0f, 10.0f);
  float e = __builtin_amdgcn_exp2f(cx * 2.8853900817779268f);
  float r = __builtin_amdgcn_rcpf(e + 1.0f);
  return fmaf(-2.0f, r, 1.0f);
}
__device__ __forceinline__ float fast_sigmoid(float x) {
  float cx = __builtin_amdgcn_fmed3f(x, -30.0f, 30.0f);
  float e = __builtin_amdgcn_exp2f(cx * -1.4426950408889634f);
  return __builtin_amdgcn_rcpf(1.0f + e);
}

// element index in a [rows][Kc] f16 array, XOR-swizzled 16B (8-elem) granules
__device__ __forceinline__ int sw(int row, int col, int Kc) {
  return row * Kc + ((((col >> 3) ^ (row & 7)) << 3) | (col & 7));
}

// ---------------------------------------------------------------- zero adj
__global__ void kzero(float4* __restrict__ p, int n4) {
  int i = blockIdx.x * blockDim.x + threadIdx.x;
  int stride = gridDim.x * blockDim.x;
  float4 z = {0.f, 0.f, 0.f, 0.f};
  for (; i < n4; i += stride) p[i] = z;
}

// ----------------------------------------------- apply mask to Y (post-k2)
__global__ void kmask(float4* __restrict__ Y, const int* __restrict__ mask,
                      int n4) {
  int i = blockIdx.x * blockDim.x + threadIdx.x;
  int stride = gridDim.x * blockDim.x;
  for (; i < n4; i += stride) {
    float mk = (float)mask[i >> 5];  // 32 float4 per (b,t) row of 128
    float4 v = Y[i];
    v.x *= mk; v.y *= mk; v.z *= mk; v.w *= mk;
    Y[i] = v;
  }
}

// ---------------- K0: pack f16 weight fragments (native MFMA B-frag order)
__global__ __launch_bounds__(256) void k0_prep(
    const float* __restrict__ eWih0, const float* __restrict__ eWhh0,
    const float* __restrict__ eWih1, const float* __restrict__ eWhh1,
    unsigned short* __restrict__ Wf) {
  int t = blockIdx.x * 256 + threadIdx.x;
  if (t >= WFRAGS * 64) return;
  int fid = t >> 6, lane = t & 63;
  int ntg = fid / 14, kc = fid % 14;
  int j = ntg * 16 + (lane & 15);
  int kbase = (kc < 6 ? kc : kc - 6) * 32 + (lane >> 4) * 8;
  unsigned pk[4];
#pragma unroll
  for (int ii = 0; ii < 4; ++ii) {
    unsigned p2 = 0;
#pragma unroll
    for (int s = 0; s < 2; ++s) {
      int k = kbase + ii * 2 + s;
      float wv;
      if (kc < 6)
        wv = (k < 64) ? eWih0[j * 64 + k] : eWhh0[j * 128 + (k - 64)];
      else
        wv = (k < 128) ? eWih1[j * 128 + k] : eWhh1[j * 128 + (k - 128)];
      _Float16 h = (_Float16)wv;
      unsigned short us = *(unsigned short*)&h;
      p2 |= ((unsigned)us) << (16 * s);
    }
    pk[ii] = p2;
  }
  ((uint4*)Wf)[fid * 64 + lane] = make_uint4(pk[0], pk[1], pk[2], pk[3]);
}

// ------------------------------------------- K1: P0 = x @ Wih0^T + (bih0+bhh0)
__global__ __launch_bounds__(256) void k1_gemm(
    const float* __restrict__ x, const float* __restrict__ W,
    const float* __restrict__ bih, const float* __restrict__ bhh,
    float* __restrict__ P0) {
  __shared__ float Xs[32][132];
  __shared__ float Ws[32][132];
  const int t = threadIdx.x;
  const int ty = t >> 4, tx = t & 15;
  const int n0 = blockIdx.x * 128;
  float acc[8][8];
#pragma unroll
  for (int i = 0; i < 8; ++i)
#pragma unroll
    for (int j = 0; j < 8; ++j) acc[i][j] = 0.f;

  for (int kc = 0; kc < 256; kc += 32) {
    __syncthreads();
#pragma unroll
    for (int l = 0; l < 4; ++l) {
      int idx = t + l * 256;
      int r = idx >> 3, f4 = idx & 7;
      float4 v = *(const float4*)&x[(size_t)(n0 + r) * 256 + kc + f4 * 4];
      Xs[f4 * 4 + 0][r] = v.x; Xs[f4 * 4 + 1][r] = v.y;
      Xs[f4 * 4 + 2][r] = v.z; Xs[f4 * 4 + 3][r] = v.w;
      float4 wv = *(const float4*)&W[(size_t)r * 256 + kc + f4 * 4];
      Ws[f4 * 4 + 0][r] = wv.x; Ws[f4 * 4 + 1][r] = wv.y;
      Ws[f4 * 4 + 2][r] = wv.z; Ws[f4 * 4 + 3][r] = wv.w;
    }
    __syncthreads();
#pragma unroll
    for (int kk = 0; kk < 32; ++kk) {
      float4 xa = *(const float4*)&Xs[kk][ty * 8];
      float4 xb = *(const float4*)&Xs[kk][ty * 8 + 4];
      float4 wa = *(const float4*)&Ws[kk][tx * 8];
      float4 wb = *(const float4*)&Ws[kk][tx * 8 + 4];
      float xr[8] = {xa.x, xa.y, xa.z, xa.w, xb.x, xb.y, xb.z, xb.w};
      float wr[8] = {wa.x, wa.y, wa.z, wa.w, wb.x, wb.y, wb.z, wb.w};
#pragma unroll
      for (int i = 0; i < 8; ++i)
#pragma unroll
        for (int j = 0; j < 8; ++j) acc[i][j] += xr[i] * wr[j];
    }
  }
  float bias[8];
#pragma unroll
  for (int j = 0; j < 8; ++j) bias[j] = bih[tx * 8 + j] + bhh[tx * 8 + j];
#pragma unroll
  for (int i = 0; i < 8; ++i) {
    float4 s0 = make_float4(acc[i][0] + bias[0], acc[i][1] + bias[1],
                            acc[i][2] + bias[2], acc[i][3] + bias[3]);
    float4 s1 = make_float4(acc[i][4] + bias[4], acc[i][5] + bias[5],
                            acc[i][6] + bias[6], acc[i][7] + bias[7]);
    size_t base = (size_t)(n0 + ty * 8 + i) * 128 + tx * 8;
    *(float4*)&P0[base] = s0;
    *(float4*)&P0[base + 4] = s1;
  }
}

// ------------------------- K2 v3: graph RNN, 4 waves/block, register-resident
// weights, software-pipelined layers, 1 barrier/step. Mask application moved
// to kmask (removes a per-step global load from the L1 critical path).
__global__ __launch_bounds__(256, 1) void k2_v3(
    const float* __restrict__ P0, const float* __restrict__ Whh0,
    const float* __restrict__ Wih1, const float* __restrict__ Whh1,
    const float* __restrict__ bih1, const float* __restrict__ bhh1,
    float* __restrict__ Y) {
  __shared__ __align__(16) float r0f[2][128];
  __shared__ __align__(16) float r1f[2][128];
  __shared__ __align__(16) _Float16 r0h[2][128];
  const int tid = threadIdx.x;
  const int w = tid >> 6, l = tid & 63;
  const int row = (w & 1) * 64 + l;
  const int b = blockIdx.x;
  const bool isL0 = (w < 2);

  float Wa[128];  // Whh0 row (L0) or Whh1 row (L1)
  h2 Wb[64];      // Wih1 row packed (L1 only)
  {
    const float* src = isL0 ? (Whh0 + row * 128) : (Whh1 + row * 128);
#pragma unroll
    for (int i = 0; i < 32; ++i) {
      float4 v = *(const float4*)&src[i * 4];
      Wa[i * 4 + 0] = v.x; Wa[i * 4 + 1] = v.y;
      Wa[i * 4 + 2] = v.z; Wa[i * 4 + 3] = v.w;
    }
    if (!isL0) {
      const float* s2 = Wih1 + row * 128;
#pragma unroll
      for (int i = 0; i < 64; ++i) {
        h2 t;
        t.x = (_Float16)s2[i * 2];
        t.y = (_Float16)s2[i * 2 + 1];
        Wb[i] = t;
      }
    }
  }
  const float b1c = bih1[row] + bhh1[row];
  if (tid < 128) { r0f[1][tid] = 0.f; r1f[0][tid] = 0.f; }
  __syncthreads();

  float p0v = isL0 ? P0[((size_t)b * 512 + 0) * 128 + row] : 0.f;

  for (int s = 0; s <= 512; ++s) {
    const int cs = s & 1, ps = cs ^ 1;
    if (isL0) {
      if (s < 512) {
        float p0n = (s + 1 < 512)
                        ? P0[((size_t)b * 512 + (s + 1)) * 128 + row]
                        : 0.f;
        float acc = p0v;
        const float4* hp = (const float4*)&r0f[ps][0];
#pragma unroll
        for (int c = 0; c < 32; ++c) {
          float4 hv = hp[c];
          acc += Wa[c * 4 + 0] * hv.x + Wa[c * 4 + 1] * hv.y +
                 Wa[c * 4 + 2] * hv.z + Wa[c * 4 + 3] * hv.w;
        }
        float y = fast_tanh(acc);
        r0f[cs][row] = y;
        r0h[cs][row] = (_Float16)y;
        p0v = p0n;
      }
    } else {
      if (s >= 1) {
        const int t = s - 1;
        float acc = b1c;
        const uint4* yp4 = (const uint4*)&r0h[ps][0];
#pragma unroll
        for (int c8 = 0; c8 < 16; ++c8) {
          uint4 u = yp4[c8];
          h2 a0 = __builtin_bit_cast(h2, u.x);
          h2 a1 = __builtin_bit_cast(h2, u.y);
          h2 a2 = __builtin_bit_cast(h2, u.z);
          h2 a3 = __builtin_bit_cast(h2, u.w);
#if __has_builtin(__builtin_amdgcn_fdot2)
          acc = __builtin_amdgcn_fdot2(Wb[c8 * 4 + 0], a0, acc, false);
          acc = __builtin_amdgcn_fdot2(Wb[c8 * 4 + 1], a1, acc, false);
          acc = __builtin_amdgcn_fdot2(Wb[c8 * 4 + 2], a2, acc, false);
          acc = __builtin_amdgcn_fdot2(Wb[c8 * 4 + 3], a3, acc, false);
#else
          acc += (float)Wb[c8 * 4 + 0].x * (float)a0.x +
                 (float)Wb[c8 * 4 + 0].y * (float)a0.y;
          acc += (float)Wb[c8 * 4 + 1].x * (float)a1.x +
                 (float)Wb[c8 * 4 + 1].y * (float)a1.y;
          acc += (float)Wb[c8 * 4 + 2].x * (float)a2.x +
                 (float)Wb[c8 * 4 + 2].y * (float)a2.y;
          acc += (float)Wb[c8 * 4 + 3].x * (float)a3.x +
                 (float)Wb[c8 * 4 + 3].y * (float)a3.y;
#endif
        }
        const float4* hp = (const float4*)&r1f[ps][0];
#pragma unroll
        for (int c = 0; c < 32; ++c) {
          float4 hv = hp[c];
          acc += Wa[c * 4 + 0] * hv.x + Wa[c * 4 + 1] * hv.y +
                 Wa[c * 4 + 2] * hv.z + Wa[c * 4 + 3] * hv.w;
        }
        float y = fast_tanh(acc);
        r1f[cs][row] = y;
        Y[((size_t)b * 512 + t) * 128 + row] = y;  // unmasked; kmask follows
      }
    }
    __syncthreads();
  }
}

// ------------------------- K3 v5: edge RNN, f16 MFMA, 8 waves (512 thr),
// wave = 2 m-tiles x 2 n-tiles: each A-fragment read feeds 2 MFMAs with
// VGPR-resident B (28 frags = 112 VGPR) -> per-CU LDS reads halved vs v4.
#define LDSA 0       // A      [64][64]  f16        :  8192 B
#define LDSN0 8192   // n0     2 x [64][128] f16    : 32768 B
#define LDSN1 40960  // n1     2 x [64][128] f16    : 32768 B
#define LDSPS 73728  // psum   [4][64] f32          :  1024 B
#define LDSTOT 75776

__global__ __launch_bounds__(512, 2) void k3_edge_f16(
    const float* __restrict__ Y, const unsigned short* __restrict__ Wf,
    const float* __restrict__ bih0, const float* __restrict__ bhh0,
    const float* __restrict__ bih1, const float* __restrict__ bhh1,
    const float* __restrict__ clsW, const float* __restrict__ clsb,
    float* __restrict__ adj) {
  extern __shared__ char sm[];
  _Float16* Aq = (_Float16*)(sm + LDSA);
  _Float16* N0 = (_Float16*)(sm + LDSN0);
  _Float16* N1 = (_Float16*)(sm + LDSN1);
  float* psum = (float*)(sm + LDSPS);

  const int tid = threadIdx.x;
  const int w = tid >> 6, l = tid & 63;
  const int mg = w & 1, ng = w >> 1;  // mg: 32-node half; ng: 32-feature pair
  const int colL = l & 15, q = l >> 4;
  const int node0 = blockIdx.x * 64;

  // ---- init: A = 0, N1 (both buffers) = 0, N0 buf0 = f16(Y) swizzled
  for (int i = tid; i < 2048; i += 512) ((unsigned*)(sm + LDSA))[i] = 0u;
  for (int i = tid; i < 8192; i += 512) ((unsigned*)(sm + LDSN1))[i] = 0u;
  for (int i = tid; i < 8192; i += 512) {
    int nn = i >> 7, k = i & 127;
    float v = Y[(size_t)(node0 + nn) * 128 + k];
    N0[sw(nn, k, 128)] = (_Float16)v;
  }

  // ---- resident weight fragments: 2 n-tiles x 14 = 28 x 16B = 112 VGPR
  f16x8 Wr[2][14];
#pragma unroll
  for (int nt = 0; nt < 2; ++nt)
#pragma unroll
    for (int kc = 0; kc < 14; ++kc)
      Wr[nt][kc] =
          ((const f16x8*)Wf)[(size_t)(((2 * ng + nt) * 14) + kc) * 64 + l];

  // ---- per-lane constants
  float b0v[2], b1v[2], cwv[2];
#pragma unroll
  for (int nt = 0; nt < 2; ++nt) {
    int cg = (2 * ng + nt) * 16 + colL;
    b0v[nt] = bih0[cg] + bhh0[cg];
    b1v[nt] = bih1[cg] + bhh1[cg];
    cwv[nt] = clsW[cg];
  }
  const float cbias = clsb[0];
  const int ipos = (node0 & 511) + l;
  const int mval = min(ipos, 64);
  const int badj = node0 >> 9;

  __syncthreads();

  int p = 0;
  for (int step = 0; step < 64; ++step) {
    _Float16* n0rd = N0 + p * 8192;
    _Float16* n0wr = N0 + (p ^ 1) * 8192;
    _Float16* n1rd = N1 + p * 8192;
    _Float16* n1wr = N1 + (p ^ 1) * 8192;

    // ===== P0: n0 = tanh([A | h0] @ W0^T + b0)   (K = 64 + 128)
    f32x4 acc[2][2];
#pragma unroll
    for (int mt = 0; mt < 2; ++mt)
#pragma unroll
      for (int nt = 0; nt < 2; ++nt)
        acc[mt][nt] = (f32x4){b0v[nt], b0v[nt], b0v[nt], b0v[nt]};
#pragma unroll
    for (int kc = 0; kc < 6; ++kc) {
      f16x8 ah[2];
#pragma unroll
      for (int mt = 0; mt < 2; ++mt) {
        int row = mg * 32 + mt * 16 + colL;
        if (kc < 2) {
          int gk = kc * 4 + q;
          ah[mt] = *(const f16x8*)&Aq[row * 64 + ((gk ^ (row & 7)) << 3)];
        } else {
          int gk = (kc - 2) * 4 + q;
          ah[mt] = *(const f16x8*)&n0rd[row * 128 + ((gk ^ (row & 7)) << 3)];
        }
      }
#pragma unroll
      for (int mt = 0; mt < 2; ++mt)
#pragma unroll
        for (int nt = 0; nt < 2; ++nt)
          acc[mt][nt] = MFMAH(ah[mt], Wr[nt][kc], acc[mt][nt]);
    }
#pragma unroll
    for (int mt = 0; mt < 2; ++mt)
#pragma unroll
      for (int nt = 0; nt < 2; ++nt)
#pragma unroll
        for (int rg = 0; rg < 4; ++rg) {
          float v = fast_tanh(acc[mt][nt][rg]);
          int row = mg * 32 + mt * 16 + q * 4 + rg;
          int col = (2 * ng + nt) * 16 + colL;
          n0wr[sw(row, col, 128)] = (_Float16)v;
        }
    __syncthreads();  // bar A: n0 complete

    // ===== P1: n1 = tanh([n0 | h1] @ W1^T + b1)   (K = 128 + 128)
    f32x4 acc2[2][2];
#pragma unroll
    for (int mt = 0; mt < 2; ++mt)
#pragma unroll
      for (int nt = 0; nt < 2; ++nt)
        acc2[mt][nt] = (f32x4){b1v[nt], b1v[nt], b1v[nt], b1v[nt]};
#pragma unroll
    for (int kc = 0; kc < 8; ++kc) {
      const _Float16* src = (kc < 4) ? n0wr : n1rd;
      int gk = (kc & 3) * 4 + q;
      f16x8 ah[2];
#pragma unroll
      for (int mt = 0; mt < 2; ++mt) {
        int row = mg * 32 + mt * 16 + colL;
        ah[mt] = *(const f16x8*)&src[row * 128 + ((gk ^ (row & 7)) << 3)];
      }
#pragma unroll
      for (int mt = 0; mt < 2; ++mt)
#pragma unroll
        for (int nt = 0; nt < 2; ++nt)
          acc2[mt][nt] = MFMAH(ah[mt], Wr[nt][6 + kc], acc2[mt][nt]);
    }
    float pa[2][4];
#pragma unroll
    for (int mt = 0; mt < 2; ++mt)
#pragma unroll
      for (int rg = 0; rg < 4; ++rg) pa[mt][rg] = 0.f;
#pragma unroll
    for (int mt = 0; mt < 2; ++mt)
#pragma unroll
      for (int nt = 0; nt < 2; ++nt)
#pragma unroll
        for (int rg = 0; rg < 4; ++rg) {
          float v = fast_tanh(acc2[mt][nt][rg]);
          pa[mt][rg] += cwv[nt] * v;
          int row = mg * 32 + mt * 16 + q * 4 + rg;
          int col = (2 * ng + nt) * 16 + colL;
          n1wr[sw(row, col, 128)] = (_Float16)v;
        }
#pragma unroll
    for (int mt = 0; mt < 2; ++mt)
#pragma unroll
      for (int rg = 0; rg < 4; ++rg) {
        float s = pa[mt][rg];
        s += __shfl_xor(s, 1);
        s += __shfl_xor(s, 2);
        s += __shfl_xor(s, 4);
        s += __shfl_xor(s, 8);
        pa[mt][rg] = s;
      }
#pragma unroll
    for (int ii = 0; ii < 8; ++ii)
      if (colL == ii) {
        int row = mg * 32 + (ii >> 2) * 16 + q * 4 + (ii & 3);
        psum[ng * 64 + row] = pa[ii >> 2][ii & 3];
      }
    __syncthreads();  // bar B: psum + n1 complete

    // ===== cls: all waves redundantly compute sigmoid, write identical A
    // values; each wave reads its own writes next step (in-wave ordering).
    {
      float s = cbias + psum[l] + psum[64 + l] + psum[128 + l] +
                psum[192 + l];
      float sg = fast_sigmoid(s);
      if (step < mval)
        Aq[l * 64 + ((((step >> 3) ^ (l & 7)) << 3) | (step & 7))] =
            (_Float16)sg;
    }
    p ^= 1;
  }
  __syncthreads();  // final A visible for the scatter

  // ---- scatter band into adj from A (f16 -> f32)
  for (int idx = tid; idx < 4096; idx += 512) {
    int nn = idx >> 6, k = idx & 63;
    int nd = node0 + nn;
    int bb = nd >> 9, ii = nd & 511;
    int mm = min(ii, 64);
    if (k < mm) {
      float v = (float)Aq[sw(nn, k, 64)];
      int r = max(0, ii - 64) + k;
      adj[((size_t)bb * 512 + r) * 512 + ii] = v;
    }
  }
}

extern "C" void kernel_launch(void* const* d_in, const int* in_sizes, int n_in,
                              void* d_out, int out_size, void* d_ws,
                              size_t ws_size, hipStream_t stream) {
  const float* x = (const float*)d_in[0];
  const int* mask = (const int*)d_in[1];
  const float* gWih0 = (const float*)d_in[2];
  const float* gWhh0 = (const float*)d_in[3];
  const float* gbih0 = (const float*)d_in[4];
  const float* gbhh0 = (const float*)d_in[5];
  const float* gWih1 = (const float*)d_in[6];
  const float* gWhh1 = (const float*)d_in[7];
  const float* gbih1 = (const float*)d_in[8];
  const float* gbhh1 = (const float*)d_in[9];
  const float* eWih0 = (const float*)d_in[10];
  const float* eWhh0 = (const float*)d_in[11];
  const float* ebih0 = (const float*)d_in[12];
  const float* ebhh0 = (const float*)d_in[13];
  const float* eWih1 = (const float*)d_in[14];
  const float* eWhh1 = (const float*)d_in[15];
  const float* ebih1 = (const float*)d_in[16];
  const float* ebhh1 = (const float*)d_in[17];
  const float* clsW = (const float*)d_in[18];
  const float* clsb = (const float*)d_in[19];
  float* out = (float*)d_out;
  float* Y = out;
  float* adj = out + YSZ;
  float* P0 = adj;  // scratch overlay in adj region; wiped by kzero before k3

  unsigned short* Wf = (unsigned short*)d_ws;
  hipLaunchKernelGGL(k0_prep, dim3(28), dim3(256), 0, stream, eWih0, eWhh0,
                     eWih1, eWhh1, Wf);
  hipLaunchKernelGGL(k1_gemm, dim3(256), dim3(256), 0, stream, x, gWih0,
                     gbih0, gbhh0, P0);
  hipLaunchKernelGGL(k2_v3, dim3(64), dim3(256), 0, stream, P0, gWhh0, gWih1,
                     gWhh1, gbih1, gbhh1, Y);
  hipLaunchKernelGGL(kmask, dim3(1024), dim3(256), 0, stream, (float4*)Y,
                     mask, (int)(YSZ / 4));
  hipLaunchKernelGGL(kzero, dim3(2048), dim3(256), 0, stream, (float4*)adj,
                     (int)(ADJSZ / 4));
  hipFuncSetAttribute(reinterpret_cast<const void*>(k3_edge_f16),
                      hipFuncAttributeMaxDynamicSharedMemorySize, LDSTOT);
  hipLaunchKernelGGL(k3_edge_f16, dim3(512), dim3(512), LDSTOT, stream, Y,
                     Wf, ebih0, ebhh0, ebih1, ebhh1, clsW, clsb, adj);
}

// Round 6
// 913.069 us; speedup vs baseline: 15.0138x; 1.1423x over previous
//
#include <hip/hip_runtime.h>

#define B_ 64
#define S_ 512
#define D_ 256
#define H_ 128
#define M_ 64
#define N_ (B_ * S_)                 // 32768 nodes
#define YSZ ((size_t)N_ * H_)        // 4194304 floats
#define ADJSZ ((size_t)B_ * S_ * S_) // 16777216 floats

typedef __attribute__((ext_vector_type(8))) _Float16 f16x8;
typedef __attribute__((ext_vector_type(2))) _Float16 h2;
typedef __attribute__((ext_vector_type(4))) float f32x4;

#define MFMAH(a, b, c) __builtin_amdgcn_mfma_f32_16x16x32_f16(a, b, c, 0, 0, 0)

// weight frag store: 8 n-tiles x 14 k-chunks, 64 lanes x 16B each (f16)
#define WFRAGS (8 * 14)
#define WBYTES ((size_t)WFRAGS * 64 * 16)  // 114688

__device__ __forceinline__ float fast_tanh(float x) {
  // tanh(x) = 1 - 2/(e^{2x}+1)
  float cx = __builtin_amdgcn_fmed3f(x, -10.0f, 10.0f);
  float e = __builtin_amdgcn_exp2f(cx * 2.8853900817779268f);
  float r = __builtin_amdgcn_rcpf(e + 1.0f);
  return fmaf(-2.0f, r, 1.0f);
}
__device__ __forceinline__ float fast_sigmoid(float x) {
  float cx = __builtin_amdgcn_fmed3f(x, -30.0f, 30.0f);
  float e = __builtin_amdgcn_exp2f(cx * -1.4426950408889634f);
  return __builtin_amdgcn_rcpf(1.0f + e);
}

// element index in a [rows][Kc] f16 array, XOR-swizzled 16B (8-elem) granules
__device__ __forceinline__ int sw(int row, int col, int Kc) {
  return row * Kc + ((((col >> 3) ^ (row & 7)) << 3) | (col & 7));
}

// ---------------------------------------------------------------- zero adj
__global__ void kzero(float4* __restrict__ p, int n4) {
  int i = blockIdx.x * blockDim.x + threadIdx.x;
  int stride = gridDim.x * blockDim.x;
  float4 z = {0.f, 0.f, 0.f, 0.f};
  for (; i < n4; i += stride) p[i] = z;
}

// ----------------------------------------------- apply mask to Y (post-k2)
__global__ void kmask(float4* __restrict__ Y, const int* __restrict__ mask,
                      int n4) {
  int i = blockIdx.x * blockDim.x + threadIdx.x;
  int stride = gridDim.x * blockDim.x;
  for (; i < n4; i += stride) {
    float mk = (float)mask[i >> 5];  // 32 float4 per (b,t) row of 128
    float4 v = Y[i];
    v.x *= mk; v.y *= mk; v.z *= mk; v.w *= mk;
    Y[i] = v;
  }
}

// ---------------- K0: pack f16 weight fragments (native MFMA B-frag order)
__global__ __launch_bounds__(256) void k0_prep(
    const float* __restrict__ eWih0, const float* __restrict__ eWhh0,
    const float* __restrict__ eWih1, const float* __restrict__ eWhh1,
    unsigned short* __restrict__ Wf) {
  int t = blockIdx.x * 256 + threadIdx.x;
  if (t >= WFRAGS * 64) return;
  int fid = t >> 6, lane = t & 63;
  int ntg = fid / 14, kc = fid % 14;
  int j = ntg * 16 + (lane & 15);
  int kbase = (kc < 6 ? kc : kc - 6) * 32 + (lane >> 4) * 8;
  unsigned pk[4];
#pragma unroll
  for (int ii = 0; ii < 4; ++ii) {
    unsigned p2 = 0;
#pragma unroll
    for (int s = 0; s < 2; ++s) {
      int k = kbase + ii * 2 + s;
      float wv;
      if (kc < 6)
        wv = (k < 64) ? eWih0[j * 64 + k] : eWhh0[j * 128 + (k - 64)];
      else
        wv = (k < 128) ? eWih1[j * 128 + k] : eWhh1[j * 128 + (k - 128)];
      _Float16 h = (_Float16)wv;
      unsigned short us = *(unsigned short*)&h;
      p2 |= ((unsigned)us) << (16 * s);
    }
    pk[ii] = p2;
  }
  ((uint4*)Wf)[fid * 64 + lane] = make_uint4(pk[0], pk[1], pk[2], pk[3]);
}

// ------------------------------------------- K1: P0 = x @ Wih0^T + (bih0+bhh0)
__global__ __launch_bounds__(256) void k1_gemm(
    const float* __restrict__ x, const float* __restrict__ W,
    const float* __restrict__ bih, const float* __restrict__ bhh,
    float* __restrict__ P0) {
  __shared__ float Xs[32][132];
  __shared__ float Ws[32][132];
  const int t = threadIdx.x;
  const int ty = t >> 4, tx = t & 15;
  const int n0 = blockIdx.x * 128;
  float acc[8][8];
#pragma unroll
  for (int i = 0; i < 8; ++i)
#pragma unroll
    for (int j = 0; j < 8; ++j) acc[i][j] = 0.f;

  for (int kc = 0; kc < 256; kc += 32) {
    __syncthreads();
#pragma unroll
    for (int l = 0; l < 4; ++l) {
      int idx = t + l * 256;
      int r = idx >> 3, f4 = idx & 7;
      float4 v = *(const float4*)&x[(size_t)(n0 + r) * 256 + kc + f4 * 4];
      Xs[f4 * 4 + 0][r] = v.x; Xs[f4 * 4 + 1][r] = v.y;
      Xs[f4 * 4 + 2][r] = v.z; Xs[f4 * 4 + 3][r] = v.w;
      float4 wv = *(const float4*)&W[(size_t)r * 256 + kc + f4 * 4];
      Ws[f4 * 4 + 0][r] = wv.x; Ws[f4 * 4 + 1][r] = wv.y;
      Ws[f4 * 4 + 2][r] = wv.z; Ws[f4 * 4 + 3][r] = wv.w;
    }
    __syncthreads();
#pragma unroll
    for (int kk = 0; kk < 32; ++kk) {
      float4 xa = *(const float4*)&Xs[kk][ty * 8];
      float4 xb = *(const float4*)&Xs[kk][ty * 8 + 4];
      float4 wa = *(const float4*)&Ws[kk][tx * 8];
      float4 wb = *(const float4*)&Ws[kk][tx * 8 + 4];
      float xr[8] = {xa.x, xa.y, xa.z, xa.w, xb.x, xb.y, xb.z, xb.w};
      float wr[8] = {wa.x, wa.y, wa.z, wa.w, wb.x, wb.y, wb.z, wb.w};
#pragma unroll
      for (int i = 0; i < 8; ++i)
#pragma unroll
        for (int j = 0; j < 8; ++j) acc[i][j] += xr[i] * wr[j];
    }
  }
  float bias[8];
#pragma unroll
  for (int j = 0; j < 8; ++j) bias[j] = bih[tx * 8 + j] + bhh[tx * 8 + j];
#pragma unroll
  for (int i = 0; i < 8; ++i) {
    float4 s0 = make_float4(acc[i][0] + bias[0], acc[i][1] + bias[1],
                            acc[i][2] + bias[2], acc[i][3] + bias[3]);
    float4 s1 = make_float4(acc[i][4] + bias[4], acc[i][5] + bias[5],
                            acc[i][6] + bias[6], acc[i][7] + bias[7]);
    size_t base = (size_t)(n0 + ty * 8 + i) * 128 + tx * 8;
    *(float4*)&P0[base] = s0;
    *(float4*)&P0[base + 4] = s1;
  }
}

// ------------------------- K2 v4: graph RNN, 8 waves (512 thr).
// Waves 0-3 = layer0, waves 4-7 = layer1. Each output row handled by a LANE
// PAIR (k-split 64/64): per-lane weights 16xfloat4 (+16 uint of f16 for L1's
// Wih1 half) -> genuinely register-resident (v3 spilled: VGPR=112 < declared
// 192/lane). 4 independent accumulators break the FMA dep chain; shfl_xor(1)
// combines the pair; half0 writes LDS state, half1 writes Y. 1 barrier/step.
__global__ __launch_bounds__(512, 2) void k2_v4(
    const float* __restrict__ P0, const float* __restrict__ Whh0,
    const float* __restrict__ Wih1, const float* __restrict__ Whh1,
    const float* __restrict__ bih1, const float* __restrict__ bhh1,
    float* __restrict__ Y) {
  __shared__ __align__(16) float r0f[2][128];
  __shared__ __align__(16) float r1f[2][128];
  __shared__ __align__(16) _Float16 r0h[2][128];
  const int tid = threadIdx.x;
  const int g = tid & 255;           // lane id within layer group
  const bool isL0 = (tid < 256);
  const int row = g >> 1;            // output row 0..127
  const int half = g & 1;            // k-half
  const int kb = half * 64;          // k-base
  const int b = blockIdx.x;

  // resident weights: Whh row-half as 16 float4
  float4 Wa4[16];
  {
    const float* src = (isL0 ? Whh0 : Whh1) + row * 128 + kb;
#pragma unroll
    for (int i = 0; i < 16; ++i) Wa4[i] = *(const float4*)&src[i * 4];
  }
  // L1 only: Wih1 row-half as 32 h2 (packed in 16 uint4-equivalent regs)
  h2 Wb2[32];
  if (!isL0) {
    const float* s2 = Wih1 + row * 128 + kb;
#pragma unroll
    for (int i = 0; i < 32; ++i) {
      h2 t;
      t.x = (_Float16)s2[i * 2];
      t.y = (_Float16)s2[i * 2 + 1];
      Wb2[i] = t;
    }
  }
  const float b1c = (!isL0 && half == 0) ? (bih1[row] + bhh1[row]) : 0.f;
  if (tid < 128) { r0f[1][tid] = 0.f; r1f[0][tid] = 0.f; }
  __syncthreads();

  float p0v = (isL0 && half == 0) ? P0[((size_t)b * 512 + 0) * 128 + row] : 0.f;

  for (int s = 0; s <= 512; ++s) {
    const int cs = s & 1, ps = cs ^ 1;
    if (isL0) {
      if (s < 512) {
        float p0n = (half == 0 && s + 1 < 512)
                        ? P0[((size_t)b * 512 + (s + 1)) * 128 + row]
                        : 0.f;
        const float4* hp = (const float4*)&r0f[ps][kb];
        float a0 = p0v, a1 = 0.f, a2 = 0.f, a3 = 0.f;
#pragma unroll
        for (int c = 0; c < 4; ++c) {
          float4 h0v = hp[c * 4 + 0], h1v = hp[c * 4 + 1];
          float4 h2v = hp[c * 4 + 2], h3v = hp[c * 4 + 3];
          float4 w0 = Wa4[c * 4 + 0], w1 = Wa4[c * 4 + 1];
          float4 w2 = Wa4[c * 4 + 2], w3 = Wa4[c * 4 + 3];
          a0 += w0.x * h0v.x + w0.y * h0v.y + w0.z * h0v.z + w0.w * h0v.w;
          a1 += w1.x * h1v.x + w1.y * h1v.y + w1.z * h1v.z + w1.w * h1v.w;
          a2 += w2.x * h2v.x + w2.y * h2v.y + w2.z * h2v.z + w2.w * h2v.w;
          a3 += w3.x * h3v.x + w3.y * h3v.y + w3.z * h3v.z + w3.w * h3v.w;
        }
        float acc = (a0 + a1) + (a2 + a3);
        acc += __shfl_xor(acc, 1);  // combine k-halves; both lanes get sum
        float y = fast_tanh(acc);   // L0 bias folded into P0
        if (half == 0) {
          r0f[cs][row] = y;
        } else {
          r0h[cs][row] = (_Float16)y;
        }
        p0v = p0n;
      }
    } else {
      if (s >= 1) {
        const int t = s - 1;
        float a0 = b1c, a1 = 0.f, a2 = 0.f, a3 = 0.f;
        // Wih1 @ h0_t  (f16 dot2 over this lane's 64-k half)
        const uint2* yp = (const uint2*)&r0h[ps][kb];
#pragma unroll
        for (int c = 0; c < 8; ++c) {
          uint2 u = yp[c * 2 + 0];
          uint2 v = yp[c * 2 + 1];
          h2 x0 = __builtin_bit_cast(h2, u.x);
          h2 x1 = __builtin_bit_cast(h2, u.y);
          h2 x2 = __builtin_bit_cast(h2, v.x);
          h2 x3 = __builtin_bit_cast(h2, v.y);
#if __has_builtin(__builtin_amdgcn_fdot2)
          a0 = __builtin_amdgcn_fdot2(Wb2[c * 4 + 0], x0, a0, false);
          a1 = __builtin_amdgcn_fdot2(Wb2[c * 4 + 1], x1, a1, false);
          a2 = __builtin_amdgcn_fdot2(Wb2[c * 4 + 2], x2, a2, false);
          a3 = __builtin_amdgcn_fdot2(Wb2[c * 4 + 3], x3, a3, false);
#else
          a0 += (float)Wb2[c * 4 + 0].x * (float)x0.x +
                (float)Wb2[c * 4 + 0].y * (float)x0.y;
          a1 += (float)Wb2[c * 4 + 1].x * (float)x1.x +
                (float)Wb2[c * 4 + 1].y * (float)x1.y;
          a2 += (float)Wb2[c * 4 + 2].x * (float)x2.x +
                (float)Wb2[c * 4 + 2].y * (float)x2.y;
          a3 += (float)Wb2[c * 4 + 3].x * (float)x3.x +
                (float)Wb2[c * 4 + 3].y * (float)x3.y;
#endif
        }
        // Whh1 @ h1_{t-1}
        const float4* hp = (const float4*)&r1f[ps][kb];
#pragma unroll
        for (int c = 0; c < 4; ++c) {
          float4 h0v = hp[c * 4 + 0], h1v = hp[c * 4 + 1];
          float4 h2v = hp[c * 4 + 2], h3v = hp[c * 4 + 3];
          float4 w0 = Wa4[c * 4 + 0], w1 = Wa4[c * 4 + 1];
          float4 w2 = Wa4[c * 4 + 2], w3 = Wa4[c * 4 + 3];
          a0 += w0.x * h0v.x + w0.y * h0v.y + w0.z * h0v.z + w0.w * h0v.w;
          a1 += w1.x * h1v.x + w1.y * h1v.y + w1.z * h1v.z + w1.w * h1v.w;
          a2 += w2.x * h2v.x + w2.y * h2v.y + w2.z * h2v.z + w2.w * h2v.w;
          a3 += w3.x * h3v.x + w3.y * h3v.y + w3.z * h3v.z + w3.w * h3v.w;
        }
        float acc = (a0 + a1) + (a2 + a3);
        acc += __shfl_xor(acc, 1);
        float y = fast_tanh(acc);
        if (half == 0) {
          r1f[cs][row] = y;
        } else {
          Y[((size_t)b * 512 + t) * 128 + row] = y;  // unmasked; kmask follows
        }
      }
    }
    __syncthreads();
  }
}

// ------------------------- K3 v5: edge RNN, f16 MFMA, 8 waves (512 thr),
// wave = 2 m-tiles x 2 n-tiles (unchanged from R5 — passing, ~400us).
#define LDSA 0       // A      [64][64]  f16        :  8192 B
#define LDSN0 8192   // n0     2 x [64][128] f16    : 32768 B
#define LDSN1 40960  // n1     2 x [64][128] f16    : 32768 B
#define LDSPS 73728  // psum   [4][64] f32          :  1024 B
#define LDSTOT 75776

__global__ __launch_bounds__(512, 2) void k3_edge_f16(
    const float* __restrict__ Y, const unsigned short* __restrict__ Wf,
    const float* __restrict__ bih0, const float* __restrict__ bhh0,
    const float* __restrict__ bih1, const float* __restrict__ bhh1,
    const float* __restrict__ clsW, const float* __restrict__ clsb,
    float* __restrict__ adj) {
  extern __shared__ char sm[];
  _Float16* Aq = (_Float16*)(sm + LDSA);
  _Float16* N0 = (_Float16*)(sm + LDSN0);
  _Float16* N1 = (_Float16*)(sm + LDSN1);
  float* psum = (float*)(sm + LDSPS);

  const int tid = threadIdx.x;
  const int w = tid >> 6, l = tid & 63;
  const int mg = w & 1, ng = w >> 1;
  const int colL = l & 15, q = l >> 4;
  const int node0 = blockIdx.x * 64;

  for (int i = tid; i < 2048; i += 512) ((unsigned*)(sm + LDSA))[i] = 0u;
  for (int i = tid; i < 8192; i += 512) ((unsigned*)(sm + LDSN1))[i] = 0u;
  for (int i = tid; i < 8192; i += 512) {
    int nn = i >> 7, k = i & 127;
    float v = Y[(size_t)(node0 + nn) * 128 + k];
    N0[sw(nn, k, 128)] = (_Float16)v;
  }

  f16x8 Wr[2][14];
#pragma unroll
  for (int nt = 0; nt < 2; ++nt)
#pragma unroll
    for (int kc = 0; kc < 14; ++kc)
      Wr[nt][kc] =
          ((const f16x8*)Wf)[(size_t)(((2 * ng + nt) * 14) + kc) * 64 + l];

  float b0v[2], b1v[2], cwv[2];
#pragma unroll
  for (int nt = 0; nt < 2; ++nt) {
    int cg = (2 * ng + nt) * 16 + colL;
    b0v[nt] = bih0[cg] + bhh0[cg];
    b1v[nt] = bih1[cg] + bhh1[cg];
    cwv[nt] = clsW[cg];
  }
  const float cbias = clsb[0];
  const int ipos = (node0 & 511) + l;
  const int mval = min(ipos, 64);
  const int badj = node0 >> 9;

  __syncthreads();

  int p = 0;
  for (int step = 0; step < 64; ++step) {
    _Float16* n0rd = N0 + p * 8192;
    _Float16* n0wr = N0 + (p ^ 1) * 8192;
    _Float16* n1rd = N1 + p * 8192;
    _Float16* n1wr = N1 + (p ^ 1) * 8192;

    f32x4 acc[2][2];
#pragma unroll
    for (int mt = 0; mt < 2; ++mt)
#pragma unroll
      for (int nt = 0; nt < 2; ++nt)
        acc[mt][nt] = (f32x4){b0v[nt], b0v[nt], b0v[nt], b0v[nt]};
#pragma unroll
    for (int kc = 0; kc < 6; ++kc) {
      f16x8 ah[2];
#pragma unroll
      for (int mt = 0; mt < 2; ++mt) {
        int row = mg * 32 + mt * 16 + colL;
        if (kc < 2) {
          int gk = kc * 4 + q;
          ah[mt] = *(const f16x8*)&Aq[row * 64 + ((gk ^ (row & 7)) << 3)];
        } else {
          int gk = (kc - 2) * 4 + q;
          ah[mt] = *(const f16x8*)&n0rd[row * 128 + ((gk ^ (row & 7)) << 3)];
        }
      }
#pragma unroll
      for (int mt = 0; mt < 2; ++mt)
#pragma unroll
        for (int nt = 0; nt < 2; ++nt)
          acc[mt][nt] = MFMAH(ah[mt], Wr[nt][kc], acc[mt][nt]);
    }
#pragma unroll
    for (int mt = 0; mt < 2; ++mt)
#pragma unroll
      for (int nt = 0; nt < 2; ++nt)
#pragma unroll
        for (int rg = 0; rg < 4; ++rg) {
          float v = fast_tanh(acc[mt][nt][rg]);
          int row = mg * 32 + mt * 16 + q * 4 + rg;
          int col = (2 * ng + nt) * 16 + colL;
          n0wr[sw(row, col, 128)] = (_Float16)v;
        }
    __syncthreads();  // bar A: n0 complete

    f32x4 acc2[2][2];
#pragma unroll
    for (int mt = 0; mt < 2; ++mt)
#pragma unroll
      for (int nt = 0; nt < 2; ++nt)
        acc2[mt][nt] = (f32x4){b1v[nt], b1v[nt], b1v[nt], b1v[nt]};
#pragma unroll
    for (int kc = 0; kc < 8; ++kc) {
      const _Float16* src = (kc < 4) ? n0wr : n1rd;
      int gk = (kc & 3) * 4 + q;
      f16x8 ah[2];
#pragma unroll
      for (int mt = 0; mt < 2; ++mt) {
        int row = mg * 32 + mt * 16 + colL;
        ah[mt] = *(const f16x8*)&src[row * 128 + ((gk ^ (row & 7)) << 3)];
      }
#pragma unroll
      for (int mt = 0; mt < 2; ++mt)
#pragma unroll
        for (int nt = 0; nt < 2; ++nt)
          acc2[mt][nt] = MFMAH(ah[mt], Wr[nt][6 + kc], acc2[mt][nt]);
    }
    float pa[2][4];
#pragma unroll
    for (int mt = 0; mt < 2; ++mt)
#pragma unroll
      for (int rg = 0; rg < 4; ++rg) pa[mt][rg] = 0.f;
#pragma unroll
    for (int mt = 0; mt < 2; ++mt)
#pragma unroll
      for (int nt = 0; nt < 2; ++nt)
#pragma unroll
        for (int rg = 0; rg < 4; ++rg) {
          float v = fast_tanh(acc2[mt][nt][rg]);
          pa[mt][rg] += cwv[nt] * v;
          int row = mg * 32 + mt * 16 + q * 4 + rg;
          int col = (2 * ng + nt) * 16 + colL;
          n1wr[sw(row, col, 128)] = (_Float16)v;
        }
#pragma unroll
    for (int mt = 0; mt < 2; ++mt)
#pragma unroll
      for (int rg = 0; rg < 4; ++rg) {
        float s = pa[mt][rg];
        s += __shfl_xor(s, 1);
        s += __shfl_xor(s, 2);
        s += __shfl_xor(s, 4);
        s += __shfl_xor(s, 8);
        pa[mt][rg] = s;
      }
#pragma unroll
    for (int ii = 0; ii < 8; ++ii)
      if (colL == ii) {
        int row = mg * 32 + (ii >> 2) * 16 + q * 4 + (ii & 3);
        psum[ng * 64 + row] = pa[ii >> 2][ii & 3];
      }
    __syncthreads();  // bar B: psum + n1 complete

    {
      float s = cbias + psum[l] + psum[64 + l] + psum[128 + l] +
                psum[192 + l];
      float sg = fast_sigmoid(s);
      if (step < mval)
        Aq[l * 64 + ((((step >> 3) ^ (l & 7)) << 3) | (step & 7))] =
            (_Float16)sg;
    }
    p ^= 1;
  }
  __syncthreads();

  for (int idx = tid; idx < 4096; idx += 512) {
    int nn = idx >> 6, k = idx & 63;
    int nd = node0 + nn;
    int bb = nd >> 9, ii = nd & 511;
    int mm = min(ii, 64);
    if (k < mm) {
      float v = (float)Aq[sw(nn, k, 64)];
      int r = max(0, ii - 64) + k;
      adj[((size_t)bb * 512 + r) * 512 + ii] = v;
    }
  }
}

extern "C" void kernel_launch(void* const* d_in, const int* in_sizes, int n_in,
                              void* d_out, int out_size, void* d_ws,
                              size_t ws_size, hipStream_t stream) {
  const float* x = (const float*)d_in[0];
  const int* mask = (const int*)d_in[1];
  const float* gWih0 = (const float*)d_in[2];
  const float* gWhh0 = (const float*)d_in[3];
  const float* gbih0 = (const float*)d_in[4];
  const float* gbhh0 = (const float*)d_in[5];
  const float* gWih1 = (const float*)d_in[6];
  const float* gWhh1 = (const float*)d_in[7];
  const float* gbih1 = (const float*)d_in[8];
  const float* gbhh1 = (const float*)d_in[9];
  const float* eWih0 = (const float*)d_in[10];
  const float* eWhh0 = (const float*)d_in[11];
  const float* ebih0 = (const float*)d_in[12];
  const float* ebhh0 = (const float*)d_in[13];
  const float* eWih1 = (const float*)d_in[14];
  const float* eWhh1 = (const float*)d_in[15];
  const float* ebih1 = (const float*)d_in[16];
  const float* ebhh1 = (const float*)d_in[17];
  const float* clsW = (const float*)d_in[18];
  const float* clsb = (const float*)d_in[19];
  float* out = (float*)d_out;
  float* Y = out;
  float* adj = out + YSZ;
  float* P0 = adj;  // scratch overlay in adj region; wiped by kzero before k3

  unsigned short* Wf = (unsigned short*)d_ws;
  hipLaunchKernelGGL(k0_prep, dim3(28), dim3(256), 0, stream, eWih0, eWhh0,
                     eWih1, eWhh1, Wf);
  hipLaunchKernelGGL(k1_gemm, dim3(256), dim3(256), 0, stream, x, gWih0,
                     gbih0, gbhh0, P0);
  hipLaunchKernelGGL(k2_v4, dim3(64), dim3(512), 0, stream, P0, gWhh0, gWih1,
                     gWhh1, gbih1, gbhh1, Y);
  hipLaunchKernelGGL(kmask, dim3(1024), dim3(256), 0, stream, (float4*)Y,
                     mask, (int)(YSZ / 4));
  hipLaunchKernelGGL(kzero, dim3(2048), dim3(256), 0, stream, (float4*)adj,
                     (int)(ADJSZ / 4));
  hipFuncSetAttribute(reinterpret_cast<const void*>(k3_edge_f16),
                      hipFuncAttributeMaxDynamicSharedMemorySize, LDSTOT);
  hipLaunchKernelGGL(k3_edge_f16, dim3(512), dim3(512), LDSTOT, stream, Y,
                     Wf, ebih0, ebhh0, ebih1, ebhh1, clsW, clsb, adj);
}